// Round 1
// baseline (906.131 us; speedup 1.0000x reference)
//
#include <hip/hip_runtime.h>
#include <hip/hip_bf16.h>

#define N_NODES 100000
#define FDIM 128
#define RREL 3
#define NEDGE 262144
#define SLOPE 0.2f

// -------- workspace layout (bytes) --------
// t    : N*F floats           @ 0          (51,200,000)
// ps   : R*N floats           @ 51,200,000 ( 1,200,000)
// pd   : R*N floats           @ 52,400,000 ( 1,200,000)
// exps : R*E floats           @ 53,600,000 ( 3,145,728)
// sums : 4 floats             @ 56,745,728
// total ~56.75 MB

// Per-node attention projections: ps[r][n] = x[n]·w_s[r], pd[r][n] = x[n]·w_d[r]
__global__ void proj_kernel(const float* __restrict__ x,
                            const float* __restrict__ att_w,
                            float* __restrict__ ps, float* __restrict__ pd) {
    const int wid  = threadIdx.x >> 6;
    const int lane = threadIdx.x & 63;
    const int n = blockIdx.x * 4 + wid;
    const float2 xv = *reinterpret_cast<const float2*>(x + (size_t)n * FDIM + lane * 2);
    float accs[RREL], accd[RREL];
#pragma unroll
    for (int r = 0; r < RREL; ++r) {
        const float2 wsv = *reinterpret_cast<const float2*>(att_w + r * 2 * FDIM + lane * 2);
        const float2 wdv = *reinterpret_cast<const float2*>(att_w + r * 2 * FDIM + FDIM + lane * 2);
        accs[r] = xv.x * wsv.x + xv.y * wsv.y;
        accd[r] = xv.x * wdv.x + xv.y * wdv.y;
    }
#pragma unroll
    for (int off = 32; off >= 1; off >>= 1) {
#pragma unroll
        for (int r = 0; r < RREL; ++r) {
            accs[r] += __shfl_xor(accs[r], off);
            accd[r] += __shfl_xor(accd[r], off);
        }
    }
    if (lane == 0) {
#pragma unroll
        for (int r = 0; r < RREL; ++r) {
            ps[r * N_NODES + n] = accs[r];
            pd[r * N_NODES + n] = accd[r];
        }
    }
}

// exps[r][e] = exp(leaky_relu(ps[src]+pd[dst]+b)); sums[r] += block partial
__global__ void score_kernel(const int* __restrict__ src, const int* __restrict__ dst,
                             const float* __restrict__ ps, const float* __restrict__ pd,
                             const float* __restrict__ att_b,
                             float* __restrict__ exps, float* __restrict__ sums) {
    const int gid = blockIdx.x * 256 + threadIdx.x;
    const int r = blockIdx.x >> 10;  // E/256 = 1024 blocks per relation
    const int s = src[gid];
    const int d = dst[gid];
    float sc = ps[r * N_NODES + s] + pd[r * N_NODES + d] + att_b[r];
    sc = sc > 0.f ? sc : SLOPE * sc;
    const float ev = __expf(sc);
    exps[gid] = ev;
    // block reduction of ev
    float v = ev;
#pragma unroll
    for (int off = 32; off >= 1; off >>= 1) v += __shfl_xor(v, off);
    __shared__ float red[4];
    if ((threadIdx.x & 63) == 0) red[threadIdx.x >> 6] = v;
    __syncthreads();
    if (threadIdx.x == 0) {
        unsafeAtomicAdd(&sums[r], red[0] + red[1] + red[2] + red[3]);
    }
}

// t = x @ tw[r] + tb[r] ; fp32 vector GEMM, 32-row x 128-col tiles
__global__ __launch_bounds__(256, 2)
void gemm_kernel(const float* __restrict__ A, const float* __restrict__ B,
                 const float* __restrict__ bias, float* __restrict__ C) {
    __shared__ float sB[FDIM * FDIM];  // 64 KB
    __shared__ float sA[32 * FDIM];    // 16 KB
    const int tid = threadIdx.x;
    const size_t row0 = (size_t)blockIdx.x * 32;
#pragma unroll
    for (int i = 0; i < 16; ++i) {
        const int idx = tid * 4 + i * 1024;
        *reinterpret_cast<float4*>(&sB[idx]) = *reinterpret_cast<const float4*>(&B[idx]);
    }
#pragma unroll
    for (int i = 0; i < 4; ++i) {
        const int idx = tid * 4 + i * 1024;
        *reinterpret_cast<float4*>(&sA[idx]) = *reinterpret_cast<const float4*>(&A[row0 * FDIM + idx]);
    }
    __syncthreads();
    const int rg = tid >> 5;       // 0..7  -> rows rg*4..+3
    const int cg = tid & 31;       // 0..31 -> cols cg*4..+3
    const int c0 = cg * 4;
    float acc[4][4] = {};
    for (int k = 0; k < FDIM; k += 4) {
        float4 a[4], b[4];
#pragma unroll
        for (int i = 0; i < 4; ++i)
            a[i] = *reinterpret_cast<const float4*>(&sA[(rg * 4 + i) * FDIM + k]);
#pragma unroll
        for (int kk = 0; kk < 4; ++kk)
            b[kk] = *reinterpret_cast<const float4*>(&sB[(k + kk) * FDIM + c0]);
#pragma unroll
        for (int i = 0; i < 4; ++i) {
            const float av[4] = {a[i].x, a[i].y, a[i].z, a[i].w};
#pragma unroll
            for (int kk = 0; kk < 4; ++kk) {
                acc[i][0] += av[kk] * b[kk].x;
                acc[i][1] += av[kk] * b[kk].y;
                acc[i][2] += av[kk] * b[kk].z;
                acc[i][3] += av[kk] * b[kk].w;
            }
        }
    }
    const float4 b4 = *reinterpret_cast<const float4*>(&bias[c0]);
#pragma unroll
    for (int i = 0; i < 4; ++i) {
        float4 o;
        o.x = acc[i][0] + b4.x;
        o.y = acc[i][1] + b4.y;
        o.z = acc[i][2] + b4.z;
        o.w = acc[i][3] + b4.w;
        *reinterpret_cast<float4*>(&C[(row0 + rg * 4 + i) * FDIM + c0]) = o;
    }
}

// out[dst] += t[src] * (exps[e]/sum) ; one wave per edge, float2 per lane
__global__ void scatter_kernel(const int* __restrict__ src, const int* __restrict__ dst,
                               const float* __restrict__ exps, const float* __restrict__ sum_r,
                               const float* __restrict__ t, float* __restrict__ out) {
    const int wid  = threadIdx.x >> 6;
    const int lane = threadIdx.x & 63;
    const int e = blockIdx.x * 4 + wid;
    const int s = src[e];
    const int d = dst[e];
    const float a = exps[e] / (*sum_r);
    const float2 v = *reinterpret_cast<const float2*>(&t[(size_t)s * FDIM + lane * 2]);
    float* o = &out[(size_t)d * FDIM + lane * 2];
    unsafeAtomicAdd(o,     v.x * a);
    unsafeAtomicAdd(o + 1, v.y * a);
}

// out = relu(out + h_bias)
__global__ void finalize_kernel(float* __restrict__ out, const float* __restrict__ h_bias) {
    const int gid = blockIdx.x * 256 + threadIdx.x;  // float4 index
    const int off = gid * 4;
    float4 v = *reinterpret_cast<float4*>(&out[off]);
    const float4 b = *reinterpret_cast<const float4*>(&h_bias[off & (FDIM - 1)]);
    v.x = fmaxf(v.x + b.x, 0.f);
    v.y = fmaxf(v.y + b.y, 0.f);
    v.z = fmaxf(v.z + b.z, 0.f);
    v.w = fmaxf(v.w + b.w, 0.f);
    *reinterpret_cast<float4*>(&out[off]) = v;
}

extern "C" void kernel_launch(void* const* d_in, const int* in_sizes, int n_in,
                              void* d_out, int out_size, void* d_ws, size_t ws_size,
                              hipStream_t stream) {
    const float* x      = (const float*)d_in[0];
    const float* att_w  = (const float*)d_in[1];
    const float* att_b  = (const float*)d_in[2];
    const float* tw     = (const float*)d_in[3];
    const float* tb     = (const float*)d_in[4];
    const float* h_bias = (const float*)d_in[5];
    const int*   src    = (const int*)d_in[6];
    const int*   dst    = (const int*)d_in[7];
    float* out = (float*)d_out;

    char* ws = (char*)d_ws;
    float* t    = (float*)(ws);
    float* ps   = (float*)(ws + 51200000);
    float* pd   = (float*)(ws + 52400000);
    float* exps = (float*)(ws + 53600000);
    float* sums = (float*)(ws + 56745728);

    hipMemsetAsync(d_out, 0, (size_t)N_NODES * FDIM * sizeof(float), stream);
    hipMemsetAsync(sums, 0, 4 * sizeof(float), stream);

    proj_kernel<<<N_NODES / 4, 256, 0, stream>>>(x, att_w, ps, pd);
    score_kernel<<<RREL * NEDGE / 256, 256, 0, stream>>>(src, dst, ps, pd, att_b, exps, sums);

    for (int r = 0; r < RREL; ++r) {
        gemm_kernel<<<N_NODES / 32, 256, 0, stream>>>(x, tw + r * FDIM * FDIM, tb + r * FDIM, t);
        scatter_kernel<<<NEDGE / 4, 256, 0, stream>>>(src + r * NEDGE, dst + r * NEDGE,
                                                      exps + r * NEDGE, sums + r, t, out);
    }
    finalize_kernel<<<N_NODES * FDIM / 4 / 256, 256, 0, stream>>>(out, h_bias);
}

// Round 2
// 456.304 us; speedup vs baseline: 1.9858x; 1.9858x over previous
//
#include <hip/hip_runtime.h>
#include <hip/hip_bf16.h>

#define N_NODES 100000
#define FDIM 128
#define RREL 3
#define NEDGE 262144
#define SLOPE 0.2f
#define NCHUNK 98  // ceil(N_NODES/1024)

// -------- workspace layout (float/int units, 4 B each) --------
#define WS_PS    0          // R*N floats   (300000)
#define WS_PD    300000     // R*N floats   (300000)
#define WS_EXPS  600000     // R*E floats   (786432)
#define WS_SUMS  1386432    // 16 floats
#define WS_COUNT 1386448    // R*N ints     (300000)  histogram -> cursor -> degree
#define WS_ROWS  1686448    // R*N ints     (300000)  CSR row starts
#define WS_BSUM  1986448    // 512 ints
#define WS_EIDX  1986960    // R*E ints     (786432)
#define WS_T0    2773504    // N*F floats per t buffer (12800000 each)
#define T_ELEMS  12800000

// Per-node attention projections: ps[r][n] = x[n]·w_s[r], pd[r][n] = x[n]·w_d[r]
__global__ void proj_kernel(const float* __restrict__ x,
                            const float* __restrict__ att_w,
                            float* __restrict__ ps, float* __restrict__ pd) {
    const int wid  = threadIdx.x >> 6;
    const int lane = threadIdx.x & 63;
    const int n = blockIdx.x * 4 + wid;
    const float2 xv = *reinterpret_cast<const float2*>(x + (size_t)n * FDIM + lane * 2);
    float accs[RREL], accd[RREL];
#pragma unroll
    for (int r = 0; r < RREL; ++r) {
        const float2 wsv = *reinterpret_cast<const float2*>(att_w + r * 2 * FDIM + lane * 2);
        const float2 wdv = *reinterpret_cast<const float2*>(att_w + r * 2 * FDIM + FDIM + lane * 2);
        accs[r] = xv.x * wsv.x + xv.y * wsv.y;
        accd[r] = xv.x * wdv.x + xv.y * wdv.y;
    }
#pragma unroll
    for (int off = 32; off >= 1; off >>= 1) {
#pragma unroll
        for (int r = 0; r < RREL; ++r) {
            accs[r] += __shfl_xor(accs[r], off);
            accd[r] += __shfl_xor(accd[r], off);
        }
    }
    if (lane == 0) {
#pragma unroll
        for (int r = 0; r < RREL; ++r) {
            ps[r * N_NODES + n] = accs[r];
            pd[r * N_NODES + n] = accd[r];
        }
    }
}

// exps[r][e] = exp(leaky_relu(ps[src]+pd[dst]+b)); sums[r] += partial; count[r][dst]++
__global__ void score_kernel(const int* __restrict__ src, const int* __restrict__ dst,
                             const float* __restrict__ ps, const float* __restrict__ pd,
                             const float* __restrict__ att_b,
                             float* __restrict__ exps, float* __restrict__ sums,
                             int* __restrict__ count) {
    const int gid = blockIdx.x * 256 + threadIdx.x;
    const int r = blockIdx.x >> 10;  // E/256 = 1024 blocks per relation
    const int s = src[gid];
    const int d = dst[gid];
    atomicAdd(&count[r * N_NODES + d], 1);
    float sc = ps[r * N_NODES + s] + pd[r * N_NODES + d] + att_b[r];
    sc = sc > 0.f ? sc : SLOPE * sc;
    const float ev = __expf(sc);
    exps[gid] = ev;
    float v = ev;
#pragma unroll
    for (int off = 32; off >= 1; off >>= 1) v += __shfl_xor(v, off);
    __shared__ float red[4];
    if ((threadIdx.x & 63) == 0) red[threadIdx.x >> 6] = v;
    __syncthreads();
    if (threadIdx.x == 0) {
        unsafeAtomicAdd(&sums[r], red[0] + red[1] + red[2] + red[3]);
    }
}

// ---- 3-kernel exclusive prefix scan of count -> row_start (per relation) ----
__global__ void scan1_kernel(const int* __restrict__ count, int* __restrict__ row_start,
                             int* __restrict__ bsum) {
    const int r = blockIdx.x / NCHUNK;
    const int b = blockIdx.x % NCHUNK;
    const int tid = threadIdx.x;
    const int base = b * 1024 + tid * 4;  // element index within relation
    int v[4];
#pragma unroll
    for (int i = 0; i < 4; ++i)
        v[i] = (base + i < N_NODES) ? count[r * N_NODES + base + i] : 0;
    const int tsum = v[0] + v[1] + v[2] + v[3];
    __shared__ int sd[256];
    sd[tid] = tsum;
    __syncthreads();
    for (int off = 1; off < 256; off <<= 1) {
        const int tv = (tid >= off) ? sd[tid - off] : 0;
        __syncthreads();
        sd[tid] += tv;
        __syncthreads();
    }
    int run = sd[tid] - tsum;  // exclusive within chunk
#pragma unroll
    for (int i = 0; i < 4; ++i) {
        if (base + i < N_NODES) row_start[r * N_NODES + base + i] = run;
        run += v[i];
    }
    if (tid == 255) bsum[blockIdx.x] = sd[255];
}

__global__ void scan2_kernel(int* __restrict__ bsum) {
    const int r = blockIdx.x;
    const int tid = threadIdx.x;
    const int v = (tid < NCHUNK) ? bsum[r * NCHUNK + tid] : 0;
    __shared__ int sd[256];
    sd[tid] = v;
    __syncthreads();
    for (int off = 1; off < 256; off <<= 1) {
        const int tv = (tid >= off) ? sd[tid - off] : 0;
        __syncthreads();
        sd[tid] += tv;
        __syncthreads();
    }
    if (tid < NCHUNK) bsum[r * NCHUNK + tid] = sd[tid] - v;  // exclusive
}

__global__ void scan3_kernel(int* __restrict__ row_start, const int* __restrict__ bsum) {
    const int r = blockIdx.x / NCHUNK;
    const int b = blockIdx.x % NCHUNK;
    const int add = bsum[blockIdx.x];
    const int base = b * 1024 + threadIdx.x * 4;
#pragma unroll
    for (int i = 0; i < 4; ++i)
        if (base + i < N_NODES) row_start[r * N_NODES + base + i] += add;
}

// bucket-fill: eidx[r][row_start[d] + cursor[d]++] = local edge id
__global__ void fill_kernel(const int* __restrict__ dst, const int* __restrict__ row_start,
                            int* __restrict__ cursor, int* __restrict__ eidx) {
    const int gid = blockIdx.x * 256 + threadIdx.x;
    const int r = blockIdx.x >> 10;
    const int d = dst[gid];
    const int pos = row_start[r * N_NODES + d] + atomicAdd(&cursor[r * N_NODES + d], 1);
    eidx[r * NEDGE + pos] = gid - r * NEDGE;
}

// t = x @ tw[r] + tb[r] ; fp32 vector GEMM, 32-row x 128-col tiles
__global__ __launch_bounds__(256, 2)
void gemm_kernel(const float* __restrict__ A, const float* __restrict__ B,
                 const float* __restrict__ bias, float* __restrict__ C) {
    __shared__ float sB[FDIM * FDIM];  // 64 KB
    __shared__ float sA[32 * FDIM];    // 16 KB
    const int tid = threadIdx.x;
    const size_t row0 = (size_t)blockIdx.x * 32;
#pragma unroll
    for (int i = 0; i < 16; ++i) {
        const int idx = tid * 4 + i * 1024;
        *reinterpret_cast<float4*>(&sB[idx]) = *reinterpret_cast<const float4*>(&B[idx]);
    }
#pragma unroll
    for (int i = 0; i < 4; ++i) {
        const int idx = tid * 4 + i * 1024;
        *reinterpret_cast<float4*>(&sA[idx]) = *reinterpret_cast<const float4*>(&A[row0 * FDIM + idx]);
    }
    __syncthreads();
    const int rg = tid >> 5;
    const int cg = tid & 31;
    const int c0 = cg * 4;
    float acc[4][4] = {};
    for (int k = 0; k < FDIM; k += 4) {
        float4 a[4], b[4];
#pragma unroll
        for (int i = 0; i < 4; ++i)
            a[i] = *reinterpret_cast<const float4*>(&sA[(rg * 4 + i) * FDIM + k]);
#pragma unroll
        for (int kk = 0; kk < 4; ++kk)
            b[kk] = *reinterpret_cast<const float4*>(&sB[(k + kk) * FDIM + c0]);
#pragma unroll
        for (int i = 0; i < 4; ++i) {
            const float av[4] = {a[i].x, a[i].y, a[i].z, a[i].w};
#pragma unroll
            for (int kk = 0; kk < 4; ++kk) {
                acc[i][0] += av[kk] * b[kk].x;
                acc[i][1] += av[kk] * b[kk].y;
                acc[i][2] += av[kk] * b[kk].z;
                acc[i][3] += av[kk] * b[kk].w;
            }
        }
    }
    const float4 b4 = *reinterpret_cast<const float4*>(&bias[c0]);
#pragma unroll
    for (int i = 0; i < 4; ++i) {
        float4 o;
        o.x = acc[i][0] + b4.x;
        o.y = acc[i][1] + b4.y;
        o.z = acc[i][2] + b4.z;
        o.w = acc[i][3] + b4.w;
        *reinterpret_cast<float4*>(&C[(row0 + rg * 4 + i) * FDIM + c0]) = o;
    }
}

// CSR gather: one wave per dst node; accumulate a*t[src] over incoming edges.
__global__ void gather_kernel(const int* __restrict__ src, const int* __restrict__ row_start,
                              const int* __restrict__ degree, const int* __restrict__ eidx,
                              const float* __restrict__ exps, const float* __restrict__ sums,
                              const float* __restrict__ t0, const float* __restrict__ t1,
                              const float* __restrict__ t2,
                              const float* __restrict__ h_bias, float* __restrict__ out,
                              int r0, int r1, int accum, int fin) {
    const int lane = threadIdx.x & 63;
    const int d = blockIdx.x * 4 + (threadIdx.x >> 6);
    float* o = out + (size_t)d * FDIM + lane * 2;
    float2 acc = make_float2(0.f, 0.f);
    if (accum) acc = *reinterpret_cast<float2*>(o);
    for (int r = r0; r < r1; ++r) {
        const float* t = (r == 0) ? t0 : ((r == 1) ? t1 : t2);
        const int beg = row_start[r * N_NODES + d];
        const int cnt = degree[r * N_NODES + d];
        const float inv = 1.f / sums[r];
        for (int i = 0; i < cnt; ++i) {
            const int e = eidx[r * NEDGE + beg + i];
            const float a = exps[r * NEDGE + e] * inv;
            const int s = src[r * NEDGE + e];
            const float2 v = *reinterpret_cast<const float2*>(t + (size_t)s * FDIM + lane * 2);
            acc.x += a * v.x;
            acc.y += a * v.y;
        }
    }
    if (fin) {
        const float2 b = *reinterpret_cast<const float2*>(h_bias + lane * 2);
        acc.x = fmaxf(acc.x + b.x, 0.f);
        acc.y = fmaxf(acc.y + b.y, 0.f);
    }
    *reinterpret_cast<float2*>(o) = acc;
}

extern "C" void kernel_launch(void* const* d_in, const int* in_sizes, int n_in,
                              void* d_out, int out_size, void* d_ws, size_t ws_size,
                              hipStream_t stream) {
    const float* x      = (const float*)d_in[0];
    const float* att_w  = (const float*)d_in[1];
    const float* att_b  = (const float*)d_in[2];
    const float* tw     = (const float*)d_in[3];
    const float* tb     = (const float*)d_in[4];
    const float* h_bias = (const float*)d_in[5];
    const int*   src    = (const int*)d_in[6];
    const int*   dst    = (const int*)d_in[7];
    float* out = (float*)d_out;

    float* wsf = (float*)d_ws;
    float* ps        = wsf + WS_PS;
    float* pd        = wsf + WS_PD;
    float* exps      = wsf + WS_EXPS;
    float* sums      = wsf + WS_SUMS;
    int*   count     = (int*)(wsf + WS_COUNT);
    int*   row_start = (int*)(wsf + WS_ROWS);
    int*   bsum      = (int*)(wsf + WS_BSUM);
    int*   eidx      = (int*)(wsf + WS_EIDX);
    float* t0        = wsf + WS_T0;

    const size_t need_fused = ((size_t)WS_T0 + 3ull * T_ELEMS) * 4ull;
    const bool fused = ws_size >= need_fused;
    float* t1 = fused ? t0 + T_ELEMS : t0;
    float* t2 = fused ? t0 + 2 * T_ELEMS : t0;

    hipMemsetAsync(sums, 0, 16 * sizeof(float), stream);
    hipMemsetAsync(count, 0, (size_t)RREL * N_NODES * sizeof(int), stream);

    proj_kernel<<<N_NODES / 4, 256, 0, stream>>>(x, att_w, ps, pd);
    score_kernel<<<RREL * NEDGE / 256, 256, 0, stream>>>(src, dst, ps, pd, att_b, exps, sums, count);

    scan1_kernel<<<RREL * NCHUNK, 256, 0, stream>>>(count, row_start, bsum);
    scan2_kernel<<<RREL, 256, 0, stream>>>(bsum);
    scan3_kernel<<<RREL * NCHUNK, 256, 0, stream>>>(row_start, bsum);

    hipMemsetAsync(count, 0, (size_t)RREL * N_NODES * sizeof(int), stream);
    fill_kernel<<<RREL * NEDGE / 256, 256, 0, stream>>>(dst, row_start, count, eidx);

    if (fused) {
        gemm_kernel<<<N_NODES / 32, 256, 0, stream>>>(x, tw + 0 * FDIM * FDIM, tb + 0 * FDIM, t0);
        gemm_kernel<<<N_NODES / 32, 256, 0, stream>>>(x, tw + 1 * FDIM * FDIM, tb + 1 * FDIM, t1);
        gemm_kernel<<<N_NODES / 32, 256, 0, stream>>>(x, tw + 2 * FDIM * FDIM, tb + 2 * FDIM, t2);
        gather_kernel<<<N_NODES / 4, 256, 0, stream>>>(src, row_start, count, eidx, exps, sums,
                                                       t0, t1, t2, h_bias, out, 0, RREL, 0, 1);
    } else {
        for (int r = 0; r < RREL; ++r) {
            gemm_kernel<<<N_NODES / 32, 256, 0, stream>>>(x, tw + r * FDIM * FDIM, tb + r * FDIM, t0);
            gather_kernel<<<N_NODES / 4, 256, 0, stream>>>(src, row_start, count, eidx, exps, sums,
                                                           t0, t0, t0, h_bias, out,
                                                           r, r + 1, r > 0, r == RREL - 1);
        }
    }
}

// Round 3
// 341.711 us; speedup vs baseline: 2.6517x; 1.3354x over previous
//
#include <hip/hip_runtime.h>
#include <hip/hip_bf16.h>

#define N_NODES 100000
#define FDIM 128
#define RREL 3
#define NEDGE 262144
#define SLOPE 0.2f
#define NCHUNK 98  // ceil(N_NODES/1024)

typedef __attribute__((ext_vector_type(8))) short bf16x8;
typedef __attribute__((ext_vector_type(4))) float f32x4;

__device__ inline unsigned short f2bf(float f) {
    __hip_bfloat16 h = __float2bfloat16(f);
    return *reinterpret_cast<unsigned short*>(&h);
}

// -------- workspace layout (float units, 4 B each) --------
#define WS_PS    0          // R*N
#define WS_PD    300000     // R*N
#define WS_EXPS  600000     // R*E
#define WS_SUMS  1386432    // 4
#define WS_INVS  1386436    // 4
#define WS_COUNT 1386440    // R*N (histogram -> cursor -> degree)
#define WS_ROWS  1686440    // R*N CSR row starts
#define WS_BSUM  1986440    // 512
#define WS_EIDX  1986952    // R*E
#define WS_ASUM  2773384    // R*N
#define WS_TWT   3073384    // 49152 bf16 = 24576 floats
#define WS_AGGB  3097960    // N*384 bf16 = 19.2M floats

// ps[r][n] = x[n]·w_s[r], pd[r][n] = x[n]·w_d[r]
__global__ void proj_kernel(const float* __restrict__ x,
                            const float* __restrict__ att_w,
                            float* __restrict__ ps, float* __restrict__ pd) {
    const int wid  = threadIdx.x >> 6;
    const int lane = threadIdx.x & 63;
    const int n = blockIdx.x * 4 + wid;
    const float2 xv = *reinterpret_cast<const float2*>(x + (size_t)n * FDIM + lane * 2);
    float accs[RREL], accd[RREL];
#pragma unroll
    for (int r = 0; r < RREL; ++r) {
        const float2 wsv = *reinterpret_cast<const float2*>(att_w + r * 2 * FDIM + lane * 2);
        const float2 wdv = *reinterpret_cast<const float2*>(att_w + r * 2 * FDIM + FDIM + lane * 2);
        accs[r] = xv.x * wsv.x + xv.y * wsv.y;
        accd[r] = xv.x * wdv.x + xv.y * wdv.y;
    }
#pragma unroll
    for (int off = 32; off >= 1; off >>= 1) {
#pragma unroll
        for (int r = 0; r < RREL; ++r) {
            accs[r] += __shfl_xor(accs[r], off);
            accd[r] += __shfl_xor(accd[r], off);
        }
    }
    if (lane == 0) {
#pragma unroll
        for (int r = 0; r < RREL; ++r) {
            ps[r * N_NODES + n] = accs[r];
            pd[r * N_NODES + n] = accd[r];
        }
    }
}

// exps[r][e] = exp(leaky_relu(...)); sums[r] += partial; count[r][dst]++
__global__ void score_kernel(const int* __restrict__ src, const int* __restrict__ dst,
                             const float* __restrict__ ps, const float* __restrict__ pd,
                             const float* __restrict__ att_b,
                             float* __restrict__ exps, float* __restrict__ sums,
                             int* __restrict__ count) {
    const int gid = blockIdx.x * 256 + threadIdx.x;
    const int r = blockIdx.x >> 10;
    const int s = src[gid];
    const int d = dst[gid];
    atomicAdd(&count[r * N_NODES + d], 1);
    float sc = ps[r * N_NODES + s] + pd[r * N_NODES + d] + att_b[r];
    sc = sc > 0.f ? sc : SLOPE * sc;
    const float ev = __expf(sc);
    exps[gid] = ev;
    float v = ev;
#pragma unroll
    for (int off = 32; off >= 1; off >>= 1) v += __shfl_xor(v, off);
    __shared__ float red[4];
    if ((threadIdx.x & 63) == 0) red[threadIdx.x >> 6] = v;
    __syncthreads();
    if (threadIdx.x == 0) {
        unsafeAtomicAdd(&sums[r], red[0] + red[1] + red[2] + red[3]);
    }
}

// ---- exclusive prefix scan of count -> row_start ----
__global__ void scan1_kernel(const int* __restrict__ count, int* __restrict__ row_start,
                             int* __restrict__ bsum) {
    const int r = blockIdx.x / NCHUNK;
    const int b = blockIdx.x % NCHUNK;
    const int tid = threadIdx.x;
    const int base = b * 1024 + tid * 4;
    int v[4];
#pragma unroll
    for (int i = 0; i < 4; ++i)
        v[i] = (base + i < N_NODES) ? count[r * N_NODES + base + i] : 0;
    const int tsum = v[0] + v[1] + v[2] + v[3];
    __shared__ int sd[256];
    sd[tid] = tsum;
    __syncthreads();
    for (int off = 1; off < 256; off <<= 1) {
        const int tv = (tid >= off) ? sd[tid - off] : 0;
        __syncthreads();
        sd[tid] += tv;
        __syncthreads();
    }
    int run = sd[tid] - tsum;
#pragma unroll
    for (int i = 0; i < 4; ++i) {
        if (base + i < N_NODES) row_start[r * N_NODES + base + i] = run;
        run += v[i];
    }
    if (tid == 255) bsum[blockIdx.x] = sd[255];
}

__global__ void scan2_kernel(int* __restrict__ bsum) {
    const int r = blockIdx.x;
    const int tid = threadIdx.x;
    const int v = (tid < NCHUNK) ? bsum[r * NCHUNK + tid] : 0;
    __shared__ int sd[256];
    sd[tid] = v;
    __syncthreads();
    for (int off = 1; off < 256; off <<= 1) {
        const int tv = (tid >= off) ? sd[tid - off] : 0;
        __syncthreads();
        sd[tid] += tv;
        __syncthreads();
    }
    if (tid < NCHUNK) bsum[r * NCHUNK + tid] = sd[tid] - v;
}

__global__ void scan3_kernel(int* __restrict__ row_start, const int* __restrict__ bsum) {
    const int r = blockIdx.x / NCHUNK;
    const int b = blockIdx.x % NCHUNK;
    const int add = bsum[blockIdx.x];
    const int base = b * 1024 + threadIdx.x * 4;
#pragma unroll
    for (int i = 0; i < 4; ++i)
        if (base + i < N_NODES) row_start[r * N_NODES + base + i] += add;
}

__global__ void fill_kernel(const int* __restrict__ dst, const int* __restrict__ row_start,
                            int* __restrict__ cursor, int* __restrict__ eidx) {
    const int gid = blockIdx.x * 256 + threadIdx.x;
    const int r = blockIdx.x >> 10;
    const int d = dst[gid];
    const int pos = row_start[r * N_NODES + d] + atomicAdd(&cursor[r * N_NODES + d], 1);
    eidx[r * NEDGE + pos] = gid - r * NEDGE;
}

// twT[c][kk] = bf16(tw[kk][c])  (tw viewed as [384][128]); also inv_sums
__global__ void cast_kernel(const float* __restrict__ tw, const float* __restrict__ sums,
                            unsigned short* __restrict__ twT, float* __restrict__ invs) {
    const int c = blockIdx.x;        // 0..127
    const int kk = threadIdx.x;      // 0..383
    twT[c * 384 + kk] = f2bf(tw[kk * 128 + c]);
    if (blockIdx.x == 0 && threadIdx.x < RREL) invs[threadIdx.x] = 1.0f / sums[threadIdx.x];
}

// CSR gather of x: aggb[d][r][f] = bf16( sum_e a_e * x[src_e][f] ); asum[r][d] = sum_e a_e
// one HALF-WAVE (32 lanes) per dst node; lane covers 4 dims (float4).
__global__ void agg_kernel(const int* __restrict__ src, const int* __restrict__ row_start,
                           const int* __restrict__ degree, const int* __restrict__ eidx,
                           const float* __restrict__ exps, const float* __restrict__ invs,
                           const float* __restrict__ x,
                           unsigned short* __restrict__ aggb, float* __restrict__ asum) {
    const int lane = threadIdx.x & 31;
    const int d = blockIdx.x * 8 + (threadIdx.x >> 5);
    if (d >= N_NODES) return;
#pragma unroll
    for (int r = 0; r < RREL; ++r) {
        const int beg = row_start[r * N_NODES + d];
        const int cnt = degree[r * N_NODES + d];
        const float inv = invs[r];
        float4 acc = make_float4(0.f, 0.f, 0.f, 0.f);
        float asacc = 0.f;
        for (int i = 0; i < cnt; ++i) {
            const int e = eidx[r * NEDGE + beg + i];
            const float a = exps[r * NEDGE + e] * inv;
            const int s = src[r * NEDGE + e];
            const float4 xv = *reinterpret_cast<const float4*>(x + (size_t)s * FDIM + lane * 4);
            acc.x += a * xv.x; acc.y += a * xv.y; acc.z += a * xv.z; acc.w += a * xv.w;
            asacc += a;
        }
        ushort4 u;
        u.x = f2bf(acc.x); u.y = f2bf(acc.y); u.z = f2bf(acc.z); u.w = f2bf(acc.w);
        *reinterpret_cast<ushort4*>(aggb + ((size_t)d * 3 + r) * FDIM + lane * 4) = u;
        if (lane == 0) asum[r * N_NODES + d] = asacc;
    }
}

// out[N][128] = relu( A[N][384](bf16) @ B[384][128](bf16, stored as Bt[128][384])
//                     + asum·tb + h_bias ),  MFMA 16x16x32 bf16
__global__ __launch_bounds__(256, 1)
void gemm_kernel(const unsigned short* __restrict__ A, const unsigned short* __restrict__ Bt,
                 const float* __restrict__ asum, const float* __restrict__ tb,
                 const float* __restrict__ h_bias, float* __restrict__ out) {
    __shared__ unsigned short sB[FDIM * 392];  // padded (+8 bf16) to break bank conflicts
    __shared__ unsigned short sA[128 * 40];    // 32 k + 8 pad
    const int tid = threadIdx.x;
    const int row0 = blockIdx.x * 128;
    // stage full B (128 cols x 384 k) once
#pragma unroll
    for (int i = 0; i < 24; ++i) {
        const int chunk = tid + i * 256;
        const int c = chunk / 48, kc = chunk % 48;
        *reinterpret_cast<int4*>(&sB[c * 392 + kc * 8]) =
            *reinterpret_cast<const int4*>(&Bt[c * 384 + kc * 8]);
    }
    const int w = tid >> 6, l = tid & 63;
    const int lr = l & 15, lk = l >> 4;
    f32x4 acc[2][8];
#pragma unroll
    for (int rt = 0; rt < 2; ++rt)
#pragma unroll
        for (int ct = 0; ct < 8; ++ct) acc[rt][ct] = (f32x4){0.f, 0.f, 0.f, 0.f};

    for (int ks = 0; ks < 12; ++ks) {
        const int k0 = ks * 32;
        __syncthreads();  // also covers sB staging on first iter
        // stage A tile: 128 rows x 32 k
#pragma unroll
        for (int i = 0; i < 2; ++i) {
            const int chunk = tid + i * 256;
            const int rrow = chunk >> 2, kc = chunk & 3;
            const int grow = row0 + rrow;
            int4 v = {0, 0, 0, 0};
            if (grow < N_NODES)
                v = *reinterpret_cast<const int4*>(&A[(size_t)grow * 384 + k0 + kc * 8]);
            *reinterpret_cast<int4*>(&sA[rrow * 40 + kc * 8]) = v;
        }
        __syncthreads();
        bf16x8 bfr[8];
#pragma unroll
        for (int ct = 0; ct < 8; ++ct)
            bfr[ct] = *reinterpret_cast<const bf16x8*>(&sB[(ct * 16 + lr) * 392 + k0 + lk * 8]);
#pragma unroll
        for (int rt = 0; rt < 2; ++rt) {
            const bf16x8 afr =
                *reinterpret_cast<const bf16x8*>(&sA[(w * 32 + rt * 16 + lr) * 40 + lk * 8]);
#pragma unroll
            for (int ct = 0; ct < 8; ++ct)
                acc[rt][ct] = __builtin_amdgcn_mfma_f32_16x16x32_bf16(afr, bfr[ct], acc[rt][ct], 0, 0, 0);
        }
    }
    // epilogue: D row = (lane>>4)*4 + reg, col = lane&15  (m89-verified layout)
#pragma unroll
    for (int rt = 0; rt < 2; ++rt) {
        const int rowbase = row0 + w * 32 + rt * 16 + lk * 4;
        float as[RREL][4];
#pragma unroll
        for (int r = 0; r < RREL; ++r)
#pragma unroll
            for (int j = 0; j < 4; ++j)
                as[r][j] = (rowbase + j < N_NODES) ? asum[r * N_NODES + rowbase + j] : 0.f;
#pragma unroll
        for (int ct = 0; ct < 8; ++ct) {
            const int col = ct * 16 + lr;
            const float hb = h_bias[col];
            const float t0 = tb[col], t1 = tb[FDIM + col], t2 = tb[2 * FDIM + col];
#pragma unroll
            for (int j = 0; j < 4; ++j) {
                const int row = rowbase + j;
                if (row < N_NODES) {
                    float v = acc[rt][ct][j] + as[0][j] * t0 + as[1][j] * t1 + as[2][j] * t2 + hb;
                    out[(size_t)row * FDIM + col] = fmaxf(v, 0.f);
                }
            }
        }
    }
}

extern "C" void kernel_launch(void* const* d_in, const int* in_sizes, int n_in,
                              void* d_out, int out_size, void* d_ws, size_t ws_size,
                              hipStream_t stream) {
    const float* x      = (const float*)d_in[0];
    const float* att_w  = (const float*)d_in[1];
    const float* att_b  = (const float*)d_in[2];
    const float* tw     = (const float*)d_in[3];
    const float* tb     = (const float*)d_in[4];
    const float* h_bias = (const float*)d_in[5];
    const int*   src    = (const int*)d_in[6];
    const int*   dst    = (const int*)d_in[7];
    float* out = (float*)d_out;

    float* wsf = (float*)d_ws;
    float* ps        = wsf + WS_PS;
    float* pd        = wsf + WS_PD;
    float* exps      = wsf + WS_EXPS;
    float* sums      = wsf + WS_SUMS;
    float* invs      = wsf + WS_INVS;
    int*   count     = (int*)(wsf + WS_COUNT);
    int*   row_start = (int*)(wsf + WS_ROWS);
    int*   bsum      = (int*)(wsf + WS_BSUM);
    int*   eidx      = (int*)(wsf + WS_EIDX);
    float* asum      = wsf + WS_ASUM;
    unsigned short* twT  = (unsigned short*)(wsf + WS_TWT);
    unsigned short* aggb = (unsigned short*)(wsf + WS_AGGB);

    hipMemsetAsync(sums, 0, 8 * sizeof(float), stream);
    hipMemsetAsync(count, 0, (size_t)RREL * N_NODES * sizeof(int), stream);

    proj_kernel<<<N_NODES / 4, 256, 0, stream>>>(x, att_w, ps, pd);
    score_kernel<<<RREL * NEDGE / 256, 256, 0, stream>>>(src, dst, ps, pd, att_b, exps, sums, count);

    scan1_kernel<<<RREL * NCHUNK, 256, 0, stream>>>(count, row_start, bsum);
    scan2_kernel<<<RREL, 256, 0, stream>>>(bsum);
    scan3_kernel<<<RREL * NCHUNK, 256, 0, stream>>>(row_start, bsum);

    hipMemsetAsync(count, 0, (size_t)RREL * N_NODES * sizeof(int), stream);
    fill_kernel<<<RREL * NEDGE / 256, 256, 0, stream>>>(dst, row_start, count, eidx);

    cast_kernel<<<FDIM, 384, 0, stream>>>(tw, sums, twT, invs);

    agg_kernel<<<N_NODES / 8, 256, 0, stream>>>(src, row_start, count, eidx, exps, invs, x,
                                                aggb, asum);

    gemm_kernel<<<(N_NODES + 127) / 128, 256, 0, stream>>>(aggb, twT, asum, tb, h_bias, out);
}

// Round 4
// 282.798 us; speedup vs baseline: 3.2042x; 1.2083x over previous
//
#include <hip/hip_runtime.h>
#include <hip/hip_bf16.h>

#define N_NODES 100000
#define FDIM 128
#define RREL 3
#define NEDGE 262144
#define SLOPE 0.2f
#define NCHUNK 98  // ceil(N_NODES/1024)

typedef __attribute__((ext_vector_type(8))) short bf16x8;
typedef __attribute__((ext_vector_type(4))) float f32x4;

__device__ inline unsigned short f2bf(float f) {
    __hip_bfloat16 h = __float2bfloat16(f);
    return *reinterpret_cast<unsigned short*>(&h);
}
__device__ inline float bf2f(unsigned short u) {
    unsigned int b = ((unsigned int)u) << 16;
    return __int_as_float(b);
}

// -------- workspace layout (float units, 4 B each) --------
#define WS_PS    0          // R*N
#define WS_PD    300000     // R*N
#define WS_SUMS  600000     // 16
#define WS_COUNT 600016     // R*N  (histogram -> cursor)
#define WS_ROWS  900016     // R*N  CSR row starts
#define WS_BSUM  1200016    // 512
#define WS_ESORT 1200528    // R*E int2 = 1572864 floats
#define WS_ASUM  2773392    // R*N
#define WS_TWT   3073392    // 49152 bf16 = 24576 floats (inv-scaled, transposed tw)
#define WS_TBS   3097968    // 384 (inv-scaled tb)
#define WS_XBF   3098352    // N*128 bf16 = 6.4M floats
#define WS_AGGB  9498352    // N*384 bf16 = 19.2M floats
// end 28698352 floats = 114.8 MB  (ws_size >= ~165 MB per round-2 evidence)

// half-wave per node: ps/pd projections + bf16 cast of x
__global__ void proj_kernel(const float* __restrict__ x,
                            const float* __restrict__ att_w,
                            float* __restrict__ ps, float* __restrict__ pd,
                            unsigned short* __restrict__ x_bf) {
    const int lane = threadIdx.x & 31;
    const int n = blockIdx.x * 8 + (threadIdx.x >> 5);
    const float4 xv = *reinterpret_cast<const float4*>(x + (size_t)n * FDIM + lane * 4);
    ushort4 u;
    u.x = f2bf(xv.x); u.y = f2bf(xv.y); u.z = f2bf(xv.z); u.w = f2bf(xv.w);
    *reinterpret_cast<ushort4*>(x_bf + (size_t)n * FDIM + lane * 4) = u;
    float accs[RREL], accd[RREL];
#pragma unroll
    for (int r = 0; r < RREL; ++r) {
        const float4 wsv = *reinterpret_cast<const float4*>(att_w + r * 2 * FDIM + lane * 4);
        const float4 wdv = *reinterpret_cast<const float4*>(att_w + r * 2 * FDIM + FDIM + lane * 4);
        accs[r] = xv.x * wsv.x + xv.y * wsv.y + xv.z * wsv.z + xv.w * wsv.w;
        accd[r] = xv.x * wdv.x + xv.y * wdv.y + xv.z * wdv.z + xv.w * wdv.w;
    }
#pragma unroll
    for (int off = 16; off >= 1; off >>= 1) {
#pragma unroll
        for (int r = 0; r < RREL; ++r) {
            accs[r] += __shfl_xor(accs[r], off);
            accd[r] += __shfl_xor(accd[r], off);
        }
    }
    if (lane == 0) {
#pragma unroll
        for (int r = 0; r < RREL; ++r) {
            ps[r * N_NODES + n] = accs[r];
            pd[r * N_NODES + n] = accd[r];
        }
    }
}

// histogram of dst per relation
__global__ void hist_kernel(const int* __restrict__ dst, int* __restrict__ count) {
    const int gid = blockIdx.x * 256 + threadIdx.x;
    const int r = blockIdx.x >> 10;
    atomicAdd(&count[r * N_NODES + dst[gid]], 1);
}

// ---- exclusive prefix scan of count -> row_start; zero count (reused as cursor) ----
__global__ void scan1_kernel(int* __restrict__ count, int* __restrict__ row_start,
                             int* __restrict__ bsum) {
    const int r = blockIdx.x / NCHUNK;
    const int b = blockIdx.x % NCHUNK;
    const int tid = threadIdx.x;
    const int base = b * 1024 + tid * 4;
    int v[4];
#pragma unroll
    for (int i = 0; i < 4; ++i)
        v[i] = (base + i < N_NODES) ? count[r * N_NODES + base + i] : 0;
    const int tsum = v[0] + v[1] + v[2] + v[3];
    __shared__ int sd[256];
    sd[tid] = tsum;
    __syncthreads();
    for (int off = 1; off < 256; off <<= 1) {
        const int tv = (tid >= off) ? sd[tid - off] : 0;
        __syncthreads();
        sd[tid] += tv;
        __syncthreads();
    }
    int run = sd[tid] - tsum;
#pragma unroll
    for (int i = 0; i < 4; ++i) {
        if (base + i < N_NODES) {
            row_start[r * N_NODES + base + i] = run;
            count[r * N_NODES + base + i] = 0;
        }
        run += v[i];
    }
    if (tid == 255) bsum[blockIdx.x] = sd[255];
}

__global__ void scan2_kernel(int* __restrict__ bsum) {
    const int r = blockIdx.x;
    const int tid = threadIdx.x;
    const int v = (tid < NCHUNK) ? bsum[r * NCHUNK + tid] : 0;
    __shared__ int sd[256];
    sd[tid] = v;
    __syncthreads();
    for (int off = 1; off < 256; off <<= 1) {
        const int tv = (tid >= off) ? sd[tid - off] : 0;
        __syncthreads();
        sd[tid] += tv;
        __syncthreads();
    }
    if (tid < NCHUNK) bsum[r * NCHUNK + tid] = sd[tid] - v;
}

__global__ void scan3_kernel(int* __restrict__ row_start, const int* __restrict__ bsum) {
    const int r = blockIdx.x / NCHUNK;
    const int b = blockIdx.x % NCHUNK;
    const int add = bsum[blockIdx.x];
    const int base = b * 1024 + threadIdx.x * 4;
#pragma unroll
    for (int i = 0; i < 4; ++i)
        if (base + i < N_NODES) row_start[r * N_NODES + base + i] += add;
}

// fused score + CSR fill: edge_sorted[pos] = (src, exp(leaky_relu(score))); sums[r] += ev
__global__ void fill_kernel(const int* __restrict__ src, const int* __restrict__ dst,
                            const float* __restrict__ ps, const float* __restrict__ pd,
                            const float* __restrict__ att_b,
                            const int* __restrict__ row_start, int* __restrict__ cursor,
                            int2* __restrict__ edge_sorted, float* __restrict__ sums) {
    const int gid = blockIdx.x * 256 + threadIdx.x;
    const int r = blockIdx.x >> 10;
    const int s = src[gid];
    const int d = dst[gid];
    float sc = ps[r * N_NODES + s] + pd[r * N_NODES + d] + att_b[r];
    sc = sc > 0.f ? sc : SLOPE * sc;
    const float ev = __expf(sc);
    const int pos = row_start[r * N_NODES + d] + atomicAdd(&cursor[r * N_NODES + d], 1);
    int2 pk;
    pk.x = s;
    pk.y = __float_as_int(ev);
    edge_sorted[(size_t)r * NEDGE + pos] = pk;
    float v = ev;
#pragma unroll
    for (int off = 32; off >= 1; off >>= 1) v += __shfl_xor(v, off);
    __shared__ float red[4];
    if ((threadIdx.x & 63) == 0) red[threadIdx.x >> 6] = v;
    __syncthreads();
    if (threadIdx.x == 0) {
        unsafeAtomicAdd(&sums[r], red[0] + red[1] + red[2] + red[3]);
    }
}

// twT[c][k] = bf16(tw[k][c] / sums[k/128]) ; tbs[k_rel] = tb / sums   (fold softmax denom)
__global__ void cast_kernel(const float* __restrict__ tw, const float* __restrict__ tb,
                            const float* __restrict__ sums,
                            unsigned short* __restrict__ twT, float* __restrict__ tbs) {
    const int c = blockIdx.x;      // 0..127
    const int kk = threadIdx.x;    // 0..383
    const float inv = 1.0f / sums[kk >> 7];
    twT[c * 384 + kk] = f2bf(tw[kk * 128 + c] * inv);
    if (c == 0) tbs[kk] = tb[kk] * inv;
}

// CSR gather of bf16 x: aggb[n][r*128+f] = bf16( sum_e ev_e * x_bf[src_e][f] );
// asum[r][n] = sum_e ev_e.  One half-wave per (r,n); contiguous edge payload.
__global__ void agg_kernel(const int* __restrict__ row_start,
                           const int2* __restrict__ edge_sorted,
                           const unsigned short* __restrict__ x_bf,
                           unsigned short* __restrict__ aggb, float* __restrict__ asum) {
    const int lane = threadIdx.x & 31;
    const int r = blockIdx.y;
    const int n = blockIdx.x * 8 + (threadIdx.x >> 5);
    const int beg = row_start[r * N_NODES + n];
    const int end = (n == N_NODES - 1) ? NEDGE : row_start[r * N_NODES + n + 1];
    const int2* es = edge_sorted + (size_t)r * NEDGE;
    float4 acc = make_float4(0.f, 0.f, 0.f, 0.f);
    float asacc = 0.f;
    for (int i = beg; i < end; ++i) {
        const int2 pk = es[i];
        const float a = __int_as_float(pk.y);
        const ushort4 xv = *reinterpret_cast<const ushort4*>(x_bf + (size_t)pk.x * FDIM + lane * 4);
        acc.x += a * bf2f(xv.x);
        acc.y += a * bf2f(xv.y);
        acc.z += a * bf2f(xv.z);
        acc.w += a * bf2f(xv.w);
        asacc += a;
    }
    ushort4 u;
    u.x = f2bf(acc.x); u.y = f2bf(acc.y); u.z = f2bf(acc.z); u.w = f2bf(acc.w);
    *reinterpret_cast<ushort4*>(aggb + (size_t)n * 384 + r * FDIM + lane * 4) = u;
    if (lane == 0) asum[r * N_NODES + n] = asacc;
}

// out[N][128] = relu( A[N][384](bf16) @ W + asum·tbs + h_bias ), MFMA 16x16x32 bf16
__global__ __launch_bounds__(256, 1)
void gemm_kernel(const unsigned short* __restrict__ A, const unsigned short* __restrict__ Bt,
                 const float* __restrict__ asum, const float* __restrict__ tbs,
                 const float* __restrict__ h_bias, float* __restrict__ out) {
    __shared__ unsigned short sB[FDIM * 392];  // padded +8 bf16
    __shared__ unsigned short sA[128 * 40];    // 32 k + 8 pad
    const int tid = threadIdx.x;
    const int row0 = blockIdx.x * 128;
#pragma unroll
    for (int i = 0; i < 24; ++i) {
        const int chunk = tid + i * 256;
        const int c = chunk / 48, kc = chunk % 48;
        *reinterpret_cast<int4*>(&sB[c * 392 + kc * 8]) =
            *reinterpret_cast<const int4*>(&Bt[c * 384 + kc * 8]);
    }
    const int w = tid >> 6, l = tid & 63;
    const int lr = l & 15, lk = l >> 4;
    f32x4 acc[2][8];
#pragma unroll
    for (int rt = 0; rt < 2; ++rt)
#pragma unroll
        for (int ct = 0; ct < 8; ++ct) acc[rt][ct] = (f32x4){0.f, 0.f, 0.f, 0.f};

    for (int ks = 0; ks < 12; ++ks) {
        const int k0 = ks * 32;
        __syncthreads();
#pragma unroll
        for (int i = 0; i < 2; ++i) {
            const int chunk = tid + i * 256;
            const int rrow = chunk >> 2, kc = chunk & 3;
            const int grow = row0 + rrow;
            int4 v = {0, 0, 0, 0};
            if (grow < N_NODES)
                v = *reinterpret_cast<const int4*>(&A[(size_t)grow * 384 + k0 + kc * 8]);
            *reinterpret_cast<int4*>(&sA[rrow * 40 + kc * 8]) = v;
        }
        __syncthreads();
        bf16x8 bfr[8];
#pragma unroll
        for (int ct = 0; ct < 8; ++ct)
            bfr[ct] = *reinterpret_cast<const bf16x8*>(&sB[(ct * 16 + lr) * 392 + k0 + lk * 8]);
#pragma unroll
        for (int rt = 0; rt < 2; ++rt) {
            const bf16x8 afr =
                *reinterpret_cast<const bf16x8*>(&sA[(w * 32 + rt * 16 + lr) * 40 + lk * 8]);
#pragma unroll
            for (int ct = 0; ct < 8; ++ct)
                acc[rt][ct] = __builtin_amdgcn_mfma_f32_16x16x32_bf16(afr, bfr[ct], acc[rt][ct], 0, 0, 0);
        }
    }
#pragma unroll
    for (int rt = 0; rt < 2; ++rt) {
        const int rowbase = row0 + w * 32 + rt * 16 + lk * 4;
        float as[RREL][4];
#pragma unroll
        for (int r = 0; r < RREL; ++r)
#pragma unroll
            for (int j = 0; j < 4; ++j)
                as[r][j] = (rowbase + j < N_NODES) ? asum[r * N_NODES + rowbase + j] : 0.f;
#pragma unroll
        for (int ct = 0; ct < 8; ++ct) {
            const int col = ct * 16 + lr;
            const float hb = h_bias[col];
            const float t0 = tbs[col], t1 = tbs[FDIM + col], t2 = tbs[2 * FDIM + col];
#pragma unroll
            for (int j = 0; j < 4; ++j) {
                const int row = rowbase + j;
                if (row < N_NODES) {
                    float v = acc[rt][ct][j] + as[0][j] * t0 + as[1][j] * t1 + as[2][j] * t2 + hb;
                    out[(size_t)row * FDIM + col] = fmaxf(v, 0.f);
                }
            }
        }
    }
}

extern "C" void kernel_launch(void* const* d_in, const int* in_sizes, int n_in,
                              void* d_out, int out_size, void* d_ws, size_t ws_size,
                              hipStream_t stream) {
    const float* x      = (const float*)d_in[0];
    const float* att_w  = (const float*)d_in[1];
    const float* att_b  = (const float*)d_in[2];
    const float* tw     = (const float*)d_in[3];
    const float* tb     = (const float*)d_in[4];
    const float* h_bias = (const float*)d_in[5];
    const int*   src    = (const int*)d_in[6];
    const int*   dst    = (const int*)d_in[7];
    float* out = (float*)d_out;

    float* wsf = (float*)d_ws;
    float* ps         = wsf + WS_PS;
    float* pd         = wsf + WS_PD;
    float* sums       = wsf + WS_SUMS;
    int*   count      = (int*)(wsf + WS_COUNT);
    int*   row_start  = (int*)(wsf + WS_ROWS);
    int*   bsum       = (int*)(wsf + WS_BSUM);
    int2*  edge_sorted= (int2*)(wsf + WS_ESORT);
    float* asum       = wsf + WS_ASUM;
    unsigned short* twT  = (unsigned short*)(wsf + WS_TWT);
    float* tbs        = wsf + WS_TBS;
    unsigned short* x_bf = (unsigned short*)(wsf + WS_XBF);
    unsigned short* aggb = (unsigned short*)(wsf + WS_AGGB);

    hipMemsetAsync(sums, 0, 16 * sizeof(float), stream);
    hipMemsetAsync(count, 0, (size_t)RREL * N_NODES * sizeof(int), stream);

    proj_kernel<<<N_NODES / 8, 256, 0, stream>>>(x, att_w, ps, pd, x_bf);
    hist_kernel<<<RREL * NEDGE / 256, 256, 0, stream>>>(dst, count);

    scan1_kernel<<<RREL * NCHUNK, 256, 0, stream>>>(count, row_start, bsum);
    scan2_kernel<<<RREL, 256, 0, stream>>>(bsum);
    scan3_kernel<<<RREL * NCHUNK, 256, 0, stream>>>(row_start, bsum);

    fill_kernel<<<RREL * NEDGE / 256, 256, 0, stream>>>(src, dst, ps, pd, att_b,
                                                        row_start, count, edge_sorted, sums);

    cast_kernel<<<FDIM, 384, 0, stream>>>(tw, tb, sums, twT, tbs);

    agg_kernel<<<dim3(N_NODES / 8, RREL), 256, 0, stream>>>(row_start, edge_sorted, x_bf,
                                                            aggb, asum);

    gemm_kernel<<<(N_NODES + 127) / 128, 256, 0, stream>>>(aggb, twT, asum, tbs, h_bias, out);
}

// Round 5
// 234.529 us; speedup vs baseline: 3.8636x; 1.2058x over previous
//
#include <hip/hip_runtime.h>
#include <hip/hip_bf16.h>

#define N_NODES 100000
#define FDIM 128
#define RREL 3
#define NEDGE 262144
#define SLOPE 0.2f
#define NCHUNK 98  // ceil(N_NODES/1024)

typedef __attribute__((ext_vector_type(8))) short bf16x8;
typedef __attribute__((ext_vector_type(4))) float f32x4;

__device__ inline unsigned short f2bf(float f) {
    __hip_bfloat16 h = __float2bfloat16(f);
    return *reinterpret_cast<unsigned short*>(&h);
}
__device__ inline float bf2f(unsigned short u) {
    unsigned int b = ((unsigned int)u) << 16;
    return __int_as_float(b);
}

// -------- workspace layout (float units, 4 B each) --------
#define WS_PS    0          // R*N
#define WS_PD    300000     // R*N
#define WS_SUMS  600000     // 16
#define WS_COUNT 600016     // R*N  (histogram -> cursor)
#define WS_ROWS  900016     // R*N  CSR row starts
#define WS_BSUM  1200016    // 512
#define WS_ESORT 1200528    // R*E int2 = 1572864 floats
#define WS_ASUM  2773392    // R*N
#define WS_TWT   3073392    // 49152 bf16 = 24576 floats (inv-scaled, transposed tw)
#define WS_TBS   3097968    // 384 (inv-scaled tb)
#define WS_XBF   3098352    // N*128 bf16 = 6.4M floats
#define WS_AGGB  9498352    // N*384 bf16 = 19.2M floats

// half-wave per node: ps/pd projections + bf16 cast of x
__global__ void proj_kernel(const float* __restrict__ x,
                            const float* __restrict__ att_w,
                            float* __restrict__ ps, float* __restrict__ pd,
                            unsigned short* __restrict__ x_bf) {
    const int lane = threadIdx.x & 31;
    const int n = blockIdx.x * 8 + (threadIdx.x >> 5);
    const float4 xv = *reinterpret_cast<const float4*>(x + (size_t)n * FDIM + lane * 4);
    ushort4 u;
    u.x = f2bf(xv.x); u.y = f2bf(xv.y); u.z = f2bf(xv.z); u.w = f2bf(xv.w);
    *reinterpret_cast<ushort4*>(x_bf + (size_t)n * FDIM + lane * 4) = u;
    float accs[RREL], accd[RREL];
#pragma unroll
    for (int r = 0; r < RREL; ++r) {
        const float4 wsv = *reinterpret_cast<const float4*>(att_w + r * 2 * FDIM + lane * 4);
        const float4 wdv = *reinterpret_cast<const float4*>(att_w + r * 2 * FDIM + FDIM + lane * 4);
        accs[r] = xv.x * wsv.x + xv.y * wsv.y + xv.z * wsv.z + xv.w * wsv.w;
        accd[r] = xv.x * wdv.x + xv.y * wdv.y + xv.z * wdv.z + xv.w * wdv.w;
    }
#pragma unroll
    for (int off = 16; off >= 1; off >>= 1) {
#pragma unroll
        for (int r = 0; r < RREL; ++r) {
            accs[r] += __shfl_xor(accs[r], off);
            accd[r] += __shfl_xor(accd[r], off);
        }
    }
    if (lane == 0) {
#pragma unroll
        for (int r = 0; r < RREL; ++r) {
            ps[r * N_NODES + n] = accs[r];
            pd[r * N_NODES + n] = accd[r];
        }
    }
}

// histogram of dst per relation
__global__ void hist_kernel(const int* __restrict__ dst, int* __restrict__ count) {
    const int gid = blockIdx.x * 256 + threadIdx.x;
    const int r = blockIdx.x >> 10;
    atomicAdd(&count[r * N_NODES + dst[gid]], 1);
}

// ---- exclusive prefix scan of count -> row_start; zero count (reused as cursor) ----
__global__ void scan1_kernel(int* __restrict__ count, int* __restrict__ row_start,
                             int* __restrict__ bsum) {
    const int r = blockIdx.x / NCHUNK;
    const int b = blockIdx.x % NCHUNK;
    const int tid = threadIdx.x;
    const int base = b * 1024 + tid * 4;
    int v[4];
#pragma unroll
    for (int i = 0; i < 4; ++i)
        v[i] = (base + i < N_NODES) ? count[r * N_NODES + base + i] : 0;
    const int tsum = v[0] + v[1] + v[2] + v[3];
    __shared__ int sd[256];
    sd[tid] = tsum;
    __syncthreads();
    for (int off = 1; off < 256; off <<= 1) {
        const int tv = (tid >= off) ? sd[tid - off] : 0;
        __syncthreads();
        sd[tid] += tv;
        __syncthreads();
    }
    int run = sd[tid] - tsum;
#pragma unroll
    for (int i = 0; i < 4; ++i) {
        if (base + i < N_NODES) {
            row_start[r * N_NODES + base + i] = run;
            count[r * N_NODES + base + i] = 0;
        }
        run += v[i];
    }
    if (tid == 255) bsum[blockIdx.x] = sd[255];
}

__global__ void scan2_kernel(int* __restrict__ bsum) {
    const int r = blockIdx.x;
    const int tid = threadIdx.x;
    const int v = (tid < NCHUNK) ? bsum[r * NCHUNK + tid] : 0;
    __shared__ int sd[256];
    sd[tid] = v;
    __syncthreads();
    for (int off = 1; off < 256; off <<= 1) {
        const int tv = (tid >= off) ? sd[tid - off] : 0;
        __syncthreads();
        sd[tid] += tv;
        __syncthreads();
    }
    if (tid < NCHUNK) bsum[r * NCHUNK + tid] = sd[tid] - v;
}

__global__ void scan3_kernel(int* __restrict__ row_start, const int* __restrict__ bsum) {
    const int r = blockIdx.x / NCHUNK;
    const int b = blockIdx.x % NCHUNK;
    const int add = bsum[blockIdx.x];
    const int base = b * 1024 + threadIdx.x * 4;
#pragma unroll
    for (int i = 0; i < 4; ++i)
        if (base + i < N_NODES) row_start[r * N_NODES + base + i] += add;
}

// fused score + CSR fill: edge_sorted[pos] = (src, exp(leaky_relu(score))); sums[r] += ev
__global__ void fill_kernel(const int* __restrict__ src, const int* __restrict__ dst,
                            const float* __restrict__ ps, const float* __restrict__ pd,
                            const float* __restrict__ att_b,
                            const int* __restrict__ row_start, int* __restrict__ cursor,
                            int2* __restrict__ edge_sorted, float* __restrict__ sums) {
    const int gid = blockIdx.x * 256 + threadIdx.x;
    const int r = blockIdx.x >> 10;
    const int s = src[gid];
    const int d = dst[gid];
    float sc = ps[r * N_NODES + s] + pd[r * N_NODES + d] + att_b[r];
    sc = sc > 0.f ? sc : SLOPE * sc;
    const float ev = __expf(sc);
    const int pos = row_start[r * N_NODES + d] + atomicAdd(&cursor[r * N_NODES + d], 1);
    int2 pk;
    pk.x = s;
    pk.y = __float_as_int(ev);
    edge_sorted[(size_t)r * NEDGE + pos] = pk;
    float v = ev;
#pragma unroll
    for (int off = 32; off >= 1; off >>= 1) v += __shfl_xor(v, off);
    __shared__ float red[4];
    if ((threadIdx.x & 63) == 0) red[threadIdx.x >> 6] = v;
    __syncthreads();
    if (threadIdx.x == 0) {
        unsafeAtomicAdd(&sums[r], red[0] + red[1] + red[2] + red[3]);
    }
}

// twT[c][k] = bf16(tw[k][c] / sums[k/128]) ; tbs[k_rel] = tb / sums   (fold softmax denom)
__global__ void cast_kernel(const float* __restrict__ tw, const float* __restrict__ tb,
                            const float* __restrict__ sums,
                            unsigned short* __restrict__ twT, float* __restrict__ tbs) {
    const int c = blockIdx.x;      // 0..127
    const int kk = threadIdx.x;    // 0..383
    const float inv = 1.0f / sums[kk >> 7];
    twT[c * 384 + kk] = f2bf(tw[kk * 128 + c] * inv);
    if (c == 0) tbs[kk] = tb[kk] * inv;
}

// CSR gather of bf16 x: aggb[n][r*128+f] = bf16( sum_e ev_e * x_bf[src_e][f] );
// asum[r][n] = sum_e ev_e.  One half-wave per (r,n); contiguous edge payload.
__global__ void agg_kernel(const int* __restrict__ row_start,
                           const int2* __restrict__ edge_sorted,
                           const unsigned short* __restrict__ x_bf,
                           unsigned short* __restrict__ aggb, float* __restrict__ asum) {
    const int lane = threadIdx.x & 31;
    const int r = blockIdx.y;
    const int n = blockIdx.x * 8 + (threadIdx.x >> 5);
    const int beg = row_start[r * N_NODES + n];
    const int end = (n == N_NODES - 1) ? NEDGE : row_start[r * N_NODES + n + 1];
    const int2* es = edge_sorted + (size_t)r * NEDGE;
    float4 acc = make_float4(0.f, 0.f, 0.f, 0.f);
    float asacc = 0.f;
    for (int i = beg; i < end; ++i) {
        const int2 pk = es[i];
        const float a = __int_as_float(pk.y);
        const ushort4 xv = *reinterpret_cast<const ushort4*>(x_bf + (size_t)pk.x * FDIM + lane * 4);
        acc.x += a * bf2f(xv.x);
        acc.y += a * bf2f(xv.y);
        acc.z += a * bf2f(xv.z);
        acc.w += a * bf2f(xv.w);
        asacc += a;
    }
    ushort4 u;
    u.x = f2bf(acc.x); u.y = f2bf(acc.y); u.z = f2bf(acc.z); u.w = f2bf(acc.w);
    *reinterpret_cast<ushort4*>(aggb + (size_t)n * 384 + r * FDIM + lane * 4) = u;
    if (lane == 0) asum[r * N_NODES + n] = asacc;
}

// out[N][128] = relu( A[N][384](bf16) @ W + asum·tbs + h_bias ), MFMA 16x16x32 bf16
// BK=32, double-buffered sA+sB = 40 KB LDS -> 4 blocks/CU (16 waves/CU).
__global__ __launch_bounds__(256, 4)
void gemm_kernel(const unsigned short* __restrict__ A, const unsigned short* __restrict__ Bt,
                 const float* __restrict__ asum, const float* __restrict__ tbs,
                 const float* __restrict__ h_bias, float* __restrict__ out) {
    __shared__ unsigned short sA[2][128 * 40];  // 128 rows x (32 k + 8 pad)
    __shared__ unsigned short sB[2][128 * 40];  // 128 cols x (32 k + 8 pad)
    const int tid = threadIdx.x;
    const int row0 = blockIdx.x * 128;
    const int rs = tid >> 2;            // 0..63 (row/col group, +64 for i=1)
    const int koff = (tid & 3) * 8;     // 0,8,16,24 (element offset; 16 B chunk)

    // prologue: stage K-step 0
#pragma unroll
    for (int i = 0; i < 2; ++i) {
        const int rc = rs + i * 64;
        const int grow = row0 + rc;
        int4 va = {0, 0, 0, 0};
        if (grow < N_NODES)
            va = *reinterpret_cast<const int4*>(&A[(size_t)grow * 384 + koff]);
        *reinterpret_cast<int4*>(&sA[0][rc * 40 + koff]) = va;
        const int4 vb = *reinterpret_cast<const int4*>(&Bt[rc * 384 + koff]);
        *reinterpret_cast<int4*>(&sB[0][rc * 40 + koff]) = vb;
    }
    __syncthreads();

    const int w = tid >> 6, l = tid & 63;
    const int lr = l & 15, lk = l >> 4;
    f32x4 acc[2][8];
#pragma unroll
    for (int rt = 0; rt < 2; ++rt)
#pragma unroll
        for (int ct = 0; ct < 8; ++ct) acc[rt][ct] = (f32x4){0.f, 0.f, 0.f, 0.f};

    for (int ks = 0; ks < 12; ++ks) {
        const int buf = ks & 1;
        // issue next-tile global loads early (latency hides under MFMA below)
        int4 ra[2], rb[2];
        if (ks < 11) {
            const int k0 = (ks + 1) * 32;
#pragma unroll
            for (int i = 0; i < 2; ++i) {
                const int rc = rs + i * 64;
                const int grow = row0 + rc;
                ra[i] = make_int4(0, 0, 0, 0);
                if (grow < N_NODES)
                    ra[i] = *reinterpret_cast<const int4*>(&A[(size_t)grow * 384 + k0 + koff]);
                rb[i] = *reinterpret_cast<const int4*>(&Bt[rc * 384 + k0 + koff]);
            }
        }
        // compute on buf
        bf16x8 afr[2];
#pragma unroll
        for (int rt = 0; rt < 2; ++rt)
            afr[rt] = *reinterpret_cast<const bf16x8*>(&sA[buf][(w * 32 + rt * 16 + lr) * 40 + lk * 8]);
#pragma unroll
        for (int ct = 0; ct < 8; ++ct) {
            const bf16x8 bfr = *reinterpret_cast<const bf16x8*>(&sB[buf][(ct * 16 + lr) * 40 + lk * 8]);
            acc[0][ct] = __builtin_amdgcn_mfma_f32_16x16x32_bf16(afr[0], bfr, acc[0][ct], 0, 0, 0);
            acc[1][ct] = __builtin_amdgcn_mfma_f32_16x16x32_bf16(afr[1], bfr, acc[1][ct], 0, 0, 0);
        }
        // write prefetched tile into other buffer (after compute; vmcnt drains here)
        if (ks < 11) {
#pragma unroll
            for (int i = 0; i < 2; ++i) {
                const int rc = rs + i * 64;
                *reinterpret_cast<int4*>(&sA[buf ^ 1][rc * 40 + koff]) = ra[i];
                *reinterpret_cast<int4*>(&sB[buf ^ 1][rc * 40 + koff]) = rb[i];
            }
        }
        __syncthreads();
    }

    // epilogue: D row = (lane>>4)*4 + reg, col = lane&15  (m89-verified layout)
#pragma unroll
    for (int rt = 0; rt < 2; ++rt) {
        const int rowbase = row0 + w * 32 + rt * 16 + lk * 4;
        float as[RREL][4];
#pragma unroll
        for (int r = 0; r < RREL; ++r)
#pragma unroll
            for (int j = 0; j < 4; ++j)
                as[r][j] = (rowbase + j < N_NODES) ? asum[r * N_NODES + rowbase + j] : 0.f;
#pragma unroll
        for (int ct = 0; ct < 8; ++ct) {
            const int col = ct * 16 + lr;
            const float hb = h_bias[col];
            const float t0 = tbs[col], t1 = tbs[FDIM + col], t2 = tbs[2 * FDIM + col];
#pragma unroll
            for (int j = 0; j < 4; ++j) {
                const int row = rowbase + j;
                if (row < N_NODES) {
                    float v = acc[rt][ct][j] + as[0][j] * t0 + as[1][j] * t1 + as[2][j] * t2 + hb;
                    out[(size_t)row * FDIM + col] = fmaxf(v, 0.f);
                }
            }
        }
    }
}

extern "C" void kernel_launch(void* const* d_in, const int* in_sizes, int n_in,
                              void* d_out, int out_size, void* d_ws, size_t ws_size,
                              hipStream_t stream) {
    const float* x      = (const float*)d_in[0];
    const float* att_w  = (const float*)d_in[1];
    const float* att_b  = (const float*)d_in[2];
    const float* tw     = (const float*)d_in[3];
    const float* tb     = (const float*)d_in[4];
    const float* h_bias = (const float*)d_in[5];
    const int*   src    = (const int*)d_in[6];
    const int*   dst    = (const int*)d_in[7];
    float* out = (float*)d_out;

    float* wsf = (float*)d_ws;
    float* ps         = wsf + WS_PS;
    float* pd         = wsf + WS_PD;
    float* sums       = wsf + WS_SUMS;
    int*   count      = (int*)(wsf + WS_COUNT);
    int*   row_start  = (int*)(wsf + WS_ROWS);
    int*   bsum       = (int*)(wsf + WS_BSUM);
    int2*  edge_sorted= (int2*)(wsf + WS_ESORT);
    float* asum       = wsf + WS_ASUM;
    unsigned short* twT  = (unsigned short*)(wsf + WS_TWT);
    float* tbs        = wsf + WS_TBS;
    unsigned short* x_bf = (unsigned short*)(wsf + WS_XBF);
    unsigned short* aggb = (unsigned short*)(wsf + WS_AGGB);

    hipMemsetAsync(sums, 0, 16 * sizeof(float), stream);
    hipMemsetAsync(count, 0, (size_t)RREL * N_NODES * sizeof(int), stream);

    proj_kernel<<<N_NODES / 8, 256, 0, stream>>>(x, att_w, ps, pd, x_bf);
    hist_kernel<<<RREL * NEDGE / 256, 256, 0, stream>>>(dst, count);

    scan1_kernel<<<RREL * NCHUNK, 256, 0, stream>>>(count, row_start, bsum);
    scan2_kernel<<<RREL, 256, 0, stream>>>(bsum);
    scan3_kernel<<<RREL * NCHUNK, 256, 0, stream>>>(row_start, bsum);

    fill_kernel<<<RREL * NEDGE / 256, 256, 0, stream>>>(src, dst, ps, pd, att_b,
                                                        row_start, count, edge_sorted, sums);

    cast_kernel<<<FDIM, 384, 0, stream>>>(tw, tb, sums, twT, tbs);

    agg_kernel<<<dim3(N_NODES / 8, RREL), 256, 0, stream>>>(row_start, edge_sorted, x_bf,
                                                            aggb, asum);

    gemm_kernel<<<(N_NODES + 127) / 128, 256, 0, stream>>>(aggb, twT, asum, tbs, h_bias, out);
}

// Round 6
// 218.575 us; speedup vs baseline: 4.1456x; 1.0730x over previous
//
#include <hip/hip_runtime.h>
#include <hip/hip_bf16.h>

#define N_NODES 100000
#define FDIM 128
#define RREL 3
#define NEDGE 262144
#define SLOPE 0.2f
#define NCHUNK 98  // ceil(N_NODES/1024)
#define PROJ_BLOCKS (N_NODES / 8)          // 12500
#define HIST_BLOCKS (RREL * NEDGE / 256)   // 3072

typedef __attribute__((ext_vector_type(8))) short bf16x8;
typedef __attribute__((ext_vector_type(8))) unsigned short u16x8;
typedef __attribute__((ext_vector_type(4))) float f32x4;
typedef __attribute__((ext_vector_type(4))) int i32x4;

__device__ inline unsigned short f2bf(float f) {
    __hip_bfloat16 h = __float2bfloat16(f);
    return *reinterpret_cast<unsigned short*>(&h);
}
__device__ inline float bf2f(unsigned short u) {
    unsigned int b = ((unsigned int)u) << 16;
    return __int_as_float(b);
}

// -------- workspace layout (float units, 4 B each) --------
#define WS_PS    0          // R*N
#define WS_PD    300000     // R*N
#define WS_SUMS  600000     // 16
#define WS_COUNT 600016     // R*N  (histogram -> cursor)
#define WS_ROWS  900016     // R*N  CSR row starts
#define WS_BSUM  1200016    // 512
#define WS_ESORT 1200528    // R*E int2 = 1572864 floats
#define WS_ASUM  2773392    // R*N
#define WS_TWT   3073392    // 49152 bf16 = 24576 floats (inv-scaled, transposed tw)
#define WS_TBS   3097968    // 384 (inv-scaled tb)
#define WS_XBF   3098352    // N*128 bf16 = 6.4M floats
#define WS_AGGB  9498352    // N*384 bf16 = 19.2M floats

// fused: blocks [0, PROJ_BLOCKS) do per-node projections + bf16 cast of x;
//        blocks [PROJ_BLOCKS, +HIST_BLOCKS) histogram dst per relation.
__global__ void proj_hist_kernel(const float* __restrict__ x,
                                 const float* __restrict__ att_w,
                                 float* __restrict__ ps, float* __restrict__ pd,
                                 unsigned short* __restrict__ x_bf,
                                 const int* __restrict__ dst, int* __restrict__ count) {
    if (blockIdx.x >= PROJ_BLOCKS) {
        const int b = blockIdx.x - PROJ_BLOCKS;
        const int gid = b * 256 + threadIdx.x;
        const int r = b >> 10;
        atomicAdd(&count[r * N_NODES + dst[gid]], 1);
        return;
    }
    const int lane = threadIdx.x & 31;
    const int n = blockIdx.x * 8 + (threadIdx.x >> 5);
    const float4 xv = *reinterpret_cast<const float4*>(x + (size_t)n * FDIM + lane * 4);
    ushort4 u;
    u.x = f2bf(xv.x); u.y = f2bf(xv.y); u.z = f2bf(xv.z); u.w = f2bf(xv.w);
    *reinterpret_cast<ushort4*>(x_bf + (size_t)n * FDIM + lane * 4) = u;
    float accs[RREL], accd[RREL];
#pragma unroll
    for (int r = 0; r < RREL; ++r) {
        const float4 wsv = *reinterpret_cast<const float4*>(att_w + r * 2 * FDIM + lane * 4);
        const float4 wdv = *reinterpret_cast<const float4*>(att_w + r * 2 * FDIM + FDIM + lane * 4);
        accs[r] = xv.x * wsv.x + xv.y * wsv.y + xv.z * wsv.z + xv.w * wsv.w;
        accd[r] = xv.x * wdv.x + xv.y * wdv.y + xv.z * wdv.z + xv.w * wdv.w;
    }
#pragma unroll
    for (int off = 16; off >= 1; off >>= 1) {
#pragma unroll
        for (int r = 0; r < RREL; ++r) {
            accs[r] += __shfl_xor(accs[r], off);
            accd[r] += __shfl_xor(accd[r], off);
        }
    }
    if (lane == 0) {
#pragma unroll
        for (int r = 0; r < RREL; ++r) {
            ps[r * N_NODES + n] = accs[r];
            pd[r * N_NODES + n] = accd[r];
        }
    }
}

// ---- exclusive prefix scan of count -> row_start; zero count (reused as cursor) ----
__global__ void scan1_kernel(int* __restrict__ count, int* __restrict__ row_start,
                             int* __restrict__ bsum) {
    const int r = blockIdx.x / NCHUNK;
    const int b = blockIdx.x % NCHUNK;
    const int tid = threadIdx.x;
    const int base = b * 1024 + tid * 4;
    int v[4];
#pragma unroll
    for (int i = 0; i < 4; ++i)
        v[i] = (base + i < N_NODES) ? count[r * N_NODES + base + i] : 0;
    const int tsum = v[0] + v[1] + v[2] + v[3];
    __shared__ int sd[256];
    sd[tid] = tsum;
    __syncthreads();
    for (int off = 1; off < 256; off <<= 1) {
        const int tv = (tid >= off) ? sd[tid - off] : 0;
        __syncthreads();
        sd[tid] += tv;
        __syncthreads();
    }
    int run = sd[tid] - tsum;
#pragma unroll
    for (int i = 0; i < 4; ++i) {
        if (base + i < N_NODES) {
            row_start[r * N_NODES + base + i] = run;
            count[r * N_NODES + base + i] = 0;
        }
        run += v[i];
    }
    if (tid == 255) bsum[blockIdx.x] = sd[255];
}

__global__ void scan2_kernel(int* __restrict__ bsum) {
    const int r = blockIdx.x;
    const int tid = threadIdx.x;
    const int v = (tid < NCHUNK) ? bsum[r * NCHUNK + tid] : 0;
    __shared__ int sd[256];
    sd[tid] = v;
    __syncthreads();
    for (int off = 1; off < 256; off <<= 1) {
        const int tv = (tid >= off) ? sd[tid - off] : 0;
        __syncthreads();
        sd[tid] += tv;
        __syncthreads();
    }
    if (tid < NCHUNK) bsum[r * NCHUNK + tid] = sd[tid] - v;
}

__global__ void scan3_kernel(int* __restrict__ row_start, const int* __restrict__ bsum) {
    const int r = blockIdx.x / NCHUNK;
    const int b = blockIdx.x % NCHUNK;
    const int add = bsum[blockIdx.x];
    const int base = b * 1024 + threadIdx.x * 4;
#pragma unroll
    for (int i = 0; i < 4; ++i)
        if (base + i < N_NODES) row_start[r * N_NODES + base + i] += add;
}

// fused score + CSR fill: edge_sorted[pos] = (src, exp(leaky_relu(score))); sums[r] += ev
__global__ void fill_kernel(const int* __restrict__ src, const int* __restrict__ dst,
                            const float* __restrict__ ps, const float* __restrict__ pd,
                            const float* __restrict__ att_b,
                            const int* __restrict__ row_start, int* __restrict__ cursor,
                            int2* __restrict__ edge_sorted, float* __restrict__ sums) {
    const int gid = blockIdx.x * 256 + threadIdx.x;
    const int r = blockIdx.x >> 10;
    const int s = src[gid];
    const int d = dst[gid];
    float sc = ps[r * N_NODES + s] + pd[r * N_NODES + d] + att_b[r];
    sc = sc > 0.f ? sc : SLOPE * sc;
    const float ev = __expf(sc);
    const int pos = row_start[r * N_NODES + d] + atomicAdd(&cursor[r * N_NODES + d], 1);
    int2 pk;
    pk.x = s;
    pk.y = __float_as_int(ev);
    edge_sorted[(size_t)r * NEDGE + pos] = pk;
    float v = ev;
#pragma unroll
    for (int off = 32; off >= 1; off >>= 1) v += __shfl_xor(v, off);
    __shared__ float red[4];
    if ((threadIdx.x & 63) == 0) red[threadIdx.x >> 6] = v;
    __syncthreads();
    if (threadIdx.x == 0) {
        unsafeAtomicAdd(&sums[r], red[0] + red[1] + red[2] + red[3]);
    }
}

// twT[c][k] = bf16(tw[k][c] / sums[k/128]) ; tbs[k_rel] = tb / sums   (fold softmax denom)
__global__ void cast_kernel(const float* __restrict__ tw, const float* __restrict__ tb,
                            const float* __restrict__ sums,
                            unsigned short* __restrict__ twT, float* __restrict__ tbs) {
    const int c = blockIdx.x;      // 0..127
    const int kk = threadIdx.x;    // 0..383
    const float inv = 1.0f / sums[kk >> 7];
    twT[c * 384 + kk] = f2bf(tw[kk * 128 + c] * inv);
    if (c == 0) tbs[kk] = tb[kk] * inv;
}

// CSR gather of bf16 x: aggb[n][r*128+f] = bf16( sum_e ev_e * x_bf[src_e][f] );
// asum[r][n] = sum_e ev_e.
// One 16-LANE group per (r,n): ushort8 per lane; 4-deep edge batching for MLP;
// nontemporal aggb stores keep x_bf L2-resident.
__global__ void agg_kernel(const int* __restrict__ row_start,
                           const int2* __restrict__ edge_sorted,
                           const unsigned short* __restrict__ x_bf,
                           unsigned short* __restrict__ aggb, float* __restrict__ asum) {
    const int lane = threadIdx.x & 15;
    const int r = blockIdx.y;
    const int n = blockIdx.x * 16 + (threadIdx.x >> 4);
    const int beg = row_start[r * N_NODES + n];
    const int end = (n == N_NODES - 1) ? NEDGE : row_start[r * N_NODES + n + 1];
    const int2* es = edge_sorted + (size_t)r * NEDGE;

    float acc[8] = {0.f, 0.f, 0.f, 0.f, 0.f, 0.f, 0.f, 0.f};
    float asacc = 0.f;

    for (int i = beg; i < end; i += 4) {
        const int rem = end - i;
        // batch-load up to 4 edge payloads (independent loads)
        int2 pk0, pk1, pk2, pk3;
        pk0 = es[i];
        if (rem > 1) pk1 = es[i + 1];
        if (rem > 2) pk2 = es[i + 2];
        if (rem > 3) pk3 = es[i + 3];
        // batch-issue up to 4 x-row loads (independent)
        u16x8 xv0, xv1, xv2, xv3;
        xv0 = *reinterpret_cast<const u16x8*>(x_bf + (size_t)pk0.x * FDIM + lane * 8);
        if (rem > 1) xv1 = *reinterpret_cast<const u16x8*>(x_bf + (size_t)pk1.x * FDIM + lane * 8);
        if (rem > 2) xv2 = *reinterpret_cast<const u16x8*>(x_bf + (size_t)pk2.x * FDIM + lane * 8);
        if (rem > 3) xv3 = *reinterpret_cast<const u16x8*>(x_bf + (size_t)pk3.x * FDIM + lane * 8);
        {
            const float a = __int_as_float(pk0.y);
            asacc += a;
#pragma unroll
            for (int d = 0; d < 8; ++d) acc[d] += a * bf2f(xv0[d]);
        }
        if (rem > 1) {
            const float a = __int_as_float(pk1.y);
            asacc += a;
#pragma unroll
            for (int d = 0; d < 8; ++d) acc[d] += a * bf2f(xv1[d]);
        }
        if (rem > 2) {
            const float a = __int_as_float(pk2.y);
            asacc += a;
#pragma unroll
            for (int d = 0; d < 8; ++d) acc[d] += a * bf2f(xv2[d]);
        }
        if (rem > 3) {
            const float a = __int_as_float(pk3.y);
            asacc += a;
#pragma unroll
            for (int d = 0; d < 8; ++d) acc[d] += a * bf2f(xv3[d]);
        }
    }

    u16x8 o;
#pragma unroll
    for (int d = 0; d < 8; ++d) o[d] = f2bf(acc[d]);
    i32x4* dst4 = reinterpret_cast<i32x4*>(aggb + (size_t)n * 384 + r * FDIM + lane * 8);
    __builtin_nontemporal_store(*reinterpret_cast<i32x4*>(&o), dst4);
    if (lane == 0) asum[r * N_NODES + n] = asacc;
}

// out[N][128] = relu( A[N][384](bf16) @ W + asum·tbs + h_bias ), MFMA 16x16x32 bf16
// BK=32, double-buffered sA+sB = 40 KB LDS -> 4 blocks/CU (16 waves/CU).
__global__ __launch_bounds__(256, 4)
void gemm_kernel(const unsigned short* __restrict__ A, const unsigned short* __restrict__ Bt,
                 const float* __restrict__ asum, const float* __restrict__ tbs,
                 const float* __restrict__ h_bias, float* __restrict__ out) {
    __shared__ unsigned short sA[2][128 * 40];  // 128 rows x (32 k + 8 pad)
    __shared__ unsigned short sB[2][128 * 40];  // 128 cols x (32 k + 8 pad)
    const int tid = threadIdx.x;
    const int row0 = blockIdx.x * 128;
    const int rs = tid >> 2;            // 0..63 (row/col group, +64 for i=1)
    const int koff = (tid & 3) * 8;     // 0,8,16,24 (element offset; 16 B chunk)

    // prologue: stage K-step 0
#pragma unroll
    for (int i = 0; i < 2; ++i) {
        const int rc = rs + i * 64;
        const int grow = row0 + rc;
        int4 va = {0, 0, 0, 0};
        if (grow < N_NODES)
            va = *reinterpret_cast<const int4*>(&A[(size_t)grow * 384 + koff]);
        *reinterpret_cast<int4*>(&sA[0][rc * 40 + koff]) = va;
        const int4 vb = *reinterpret_cast<const int4*>(&Bt[rc * 384 + koff]);
        *reinterpret_cast<int4*>(&sB[0][rc * 40 + koff]) = vb;
    }
    __syncthreads();

    const int w = tid >> 6, l = tid & 63;
    const int lr = l & 15, lk = l >> 4;
    f32x4 acc[2][8];
#pragma unroll
    for (int rt = 0; rt < 2; ++rt)
#pragma unroll
        for (int ct = 0; ct < 8; ++ct) acc[rt][ct] = (f32x4){0.f, 0.f, 0.f, 0.f};

    for (int ks = 0; ks < 12; ++ks) {
        const int buf = ks & 1;
        int4 ra[2], rb[2];
        if (ks < 11) {
            const int k0 = (ks + 1) * 32;
#pragma unroll
            for (int i = 0; i < 2; ++i) {
                const int rc = rs + i * 64;
                const int grow = row0 + rc;
                ra[i] = make_int4(0, 0, 0, 0);
                if (grow < N_NODES)
                    ra[i] = *reinterpret_cast<const int4*>(&A[(size_t)grow * 384 + k0 + koff]);
                rb[i] = *reinterpret_cast<const int4*>(&Bt[rc * 384 + k0 + koff]);
            }
        }
        bf16x8 afr[2];
#pragma unroll
        for (int rt = 0; rt < 2; ++rt)
            afr[rt] = *reinterpret_cast<const bf16x8*>(&sA[buf][(w * 32 + rt * 16 + lr) * 40 + lk * 8]);
#pragma unroll
        for (int ct = 0; ct < 8; ++ct) {
            const bf16x8 bfr = *reinterpret_cast<const bf16x8*>(&sB[buf][(ct * 16 + lr) * 40 + lk * 8]);
            acc[0][ct] = __builtin_amdgcn_mfma_f32_16x16x32_bf16(afr[0], bfr, acc[0][ct], 0, 0, 0);
            acc[1][ct] = __builtin_amdgcn_mfma_f32_16x16x32_bf16(afr[1], bfr, acc[1][ct], 0, 0, 0);
        }
        if (ks < 11) {
#pragma unroll
            for (int i = 0; i < 2; ++i) {
                const int rc = rs + i * 64;
                *reinterpret_cast<int4*>(&sA[buf ^ 1][rc * 40 + koff]) = ra[i];
                *reinterpret_cast<int4*>(&sB[buf ^ 1][rc * 40 + koff]) = rb[i];
            }
        }
        __syncthreads();
    }

    // epilogue: D row = (lane>>4)*4 + reg, col = lane&15  (m89-verified layout)
#pragma unroll
    for (int rt = 0; rt < 2; ++rt) {
        const int rowbase = row0 + w * 32 + rt * 16 + lk * 4;
        float as[RREL][4];
#pragma unroll
        for (int r = 0; r < RREL; ++r)
#pragma unroll
            for (int j = 0; j < 4; ++j)
                as[r][j] = (rowbase + j < N_NODES) ? asum[r * N_NODES + rowbase + j] : 0.f;
#pragma unroll
        for (int ct = 0; ct < 8; ++ct) {
            const int col = ct * 16 + lr;
            const float hb = h_bias[col];
            const float t0 = tbs[col], t1 = tbs[FDIM + col], t2 = tbs[2 * FDIM + col];
#pragma unroll
            for (int j = 0; j < 4; ++j) {
                const int row = rowbase + j;
                if (row < N_NODES) {
                    float v = acc[rt][ct][j] + as[0][j] * t0 + as[1][j] * t1 + as[2][j] * t2 + hb;
                    out[(size_t)row * FDIM + col] = fmaxf(v, 0.f);
                }
            }
        }
    }
}

extern "C" void kernel_launch(void* const* d_in, const int* in_sizes, int n_in,
                              void* d_out, int out_size, void* d_ws, size_t ws_size,
                              hipStream_t stream) {
    const float* x      = (const float*)d_in[0];
    const float* att_w  = (const float*)d_in[1];
    const float* att_b  = (const float*)d_in[2];
    const float* tw     = (const float*)d_in[3];
    const float* tb     = (const float*)d_in[4];
    const float* h_bias = (const float*)d_in[5];
    const int*   src    = (const int*)d_in[6];
    const int*   dst    = (const int*)d_in[7];
    float* out = (float*)d_out;

    float* wsf = (float*)d_ws;
    float* ps         = wsf + WS_PS;
    float* pd         = wsf + WS_PD;
    float* sums       = wsf + WS_SUMS;
    int*   count      = (int*)(wsf + WS_COUNT);
    int*   row_start  = (int*)(wsf + WS_ROWS);
    int*   bsum       = (int*)(wsf + WS_BSUM);
    int2*  edge_sorted= (int2*)(wsf + WS_ESORT);
    float* asum       = wsf + WS_ASUM;
    unsigned short* twT  = (unsigned short*)(wsf + WS_TWT);
    float* tbs        = wsf + WS_TBS;
    unsigned short* x_bf = (unsigned short*)(wsf + WS_XBF);
    unsigned short* aggb = (unsigned short*)(wsf + WS_AGGB);

    hipMemsetAsync(sums, 0, 16 * sizeof(float), stream);
    hipMemsetAsync(count, 0, (size_t)RREL * N_NODES * sizeof(int), stream);

    proj_hist_kernel<<<PROJ_BLOCKS + HIST_BLOCKS, 256, 0, stream>>>(x, att_w, ps, pd, x_bf,
                                                                    dst, count);

    scan1_kernel<<<RREL * NCHUNK, 256, 0, stream>>>(count, row_start, bsum);
    scan2_kernel<<<RREL, 256, 0, stream>>>(bsum);
    scan3_kernel<<<RREL * NCHUNK, 256, 0, stream>>>(row_start, bsum);

    fill_kernel<<<RREL * NEDGE / 256, 256, 0, stream>>>(src, dst, ps, pd, att_b,
                                                        row_start, count, edge_sorted, sums);

    cast_kernel<<<FDIM, 384, 0, stream>>>(tw, tb, sums, twT, tbs);

    agg_kernel<<<dim3(N_NODES / 16, RREL), 256, 0, stream>>>(row_start, edge_sorted, x_bf,
                                                             aggb, asum);

    gemm_kernel<<<(N_NODES + 127) / 128, 256, 0, stream>>>(aggb, twT, asum, tbs, h_bias, out);
}

// Round 7
// 211.587 us; speedup vs baseline: 4.2825x; 1.0330x over previous
//
#include <hip/hip_runtime.h>
#include <hip/hip_bf16.h>

#define N_NODES 100000
#define FDIM 128
#define RREL 3
#define NEDGE 262144
#define SLOPE 0.2f
#define NCHUNK 98  // ceil(N_NODES/1024)
#define PROJ_BLOCKS (N_NODES / 8)          // 12500
#define HIST_BLOCKS (RREL * NEDGE / 256)   // 3072

typedef __attribute__((ext_vector_type(8))) short bf16x8;
typedef __attribute__((ext_vector_type(8))) unsigned short u16x8;
typedef __attribute__((ext_vector_type(4))) float f32x4;
typedef __attribute__((ext_vector_type(4))) int i32x4;

__device__ inline unsigned short f2bf(float f) {
    __hip_bfloat16 h = __float2bfloat16(f);
    return *reinterpret_cast<unsigned short*>(&h);
}
__device__ inline float bf2f(unsigned short u) {
    unsigned int b = ((unsigned int)u) << 16;
    return __int_as_float(b);
}

// -------- workspace layout (float units, 4 B each) --------
#define WS_PS    0          // R*N
#define WS_PD    300000     // R*N
#define WS_SUMS  600000     // 16
#define WS_COUNT 600016     // R*N  (histogram)
#define WS_ROWS  900016     // R*N  CSR row starts
#define WS_BSUM  1200016    // 512
#define WS_ESORT 1200528    // R*E int2 = 1572864 floats
#define WS_ASUM  2773392    // R*N
#define WS_TWT   3073392    // 49152 bf16 = 24576 floats (inv-scaled, transposed tw)
#define WS_TBS   3097968    // 384 (inv-scaled tb)
#define WS_XBF   3098352    // N*128 bf16 = 6.4M floats
#define WS_AGGB  9498352    // N*384 bf16 = 19.2M floats
#define WS_RANK  28698352   // R*E ints

// fused: blocks [0, PROJ_BLOCKS) do per-node projections + bf16 cast of x;
//        blocks [PROJ_BLOCKS, +HIST_BLOCKS) histogram dst per relation,
//        capturing each edge's rank within its bucket (free from the atomic).
__global__ void proj_hist_kernel(const float* __restrict__ x,
                                 const float* __restrict__ att_w,
                                 float* __restrict__ ps, float* __restrict__ pd,
                                 unsigned short* __restrict__ x_bf,
                                 const int* __restrict__ dst, int* __restrict__ count,
                                 int* __restrict__ rank) {
    if (blockIdx.x >= PROJ_BLOCKS) {
        const int b = blockIdx.x - PROJ_BLOCKS;
        const int gid = b * 256 + threadIdx.x;
        const int r = b >> 10;
        rank[gid] = atomicAdd(&count[r * N_NODES + dst[gid]], 1);
        return;
    }
    const int lane = threadIdx.x & 31;
    const int n = blockIdx.x * 8 + (threadIdx.x >> 5);
    const float4 xv = *reinterpret_cast<const float4*>(x + (size_t)n * FDIM + lane * 4);
    ushort4 u;
    u.x = f2bf(xv.x); u.y = f2bf(xv.y); u.z = f2bf(xv.z); u.w = f2bf(xv.w);
    *reinterpret_cast<ushort4*>(x_bf + (size_t)n * FDIM + lane * 4) = u;
    float accs[RREL], accd[RREL];
#pragma unroll
    for (int r = 0; r < RREL; ++r) {
        const float4 wsv = *reinterpret_cast<const float4*>(att_w + r * 2 * FDIM + lane * 4);
        const float4 wdv = *reinterpret_cast<const float4*>(att_w + r * 2 * FDIM + FDIM + lane * 4);
        accs[r] = xv.x * wsv.x + xv.y * wsv.y + xv.z * wsv.z + xv.w * wsv.w;
        accd[r] = xv.x * wdv.x + xv.y * wdv.y + xv.z * wdv.z + xv.w * wdv.w;
    }
#pragma unroll
    for (int off = 16; off >= 1; off >>= 1) {
#pragma unroll
        for (int r = 0; r < RREL; ++r) {
            accs[r] += __shfl_xor(accs[r], off);
            accd[r] += __shfl_xor(accd[r], off);
        }
    }
    if (lane == 0) {
#pragma unroll
        for (int r = 0; r < RREL; ++r) {
            ps[r * N_NODES + n] = accs[r];
            pd[r * N_NODES + n] = accd[r];
        }
    }
}

// ---- exclusive prefix scan of count -> row_start ----
__global__ void scan1_kernel(const int* __restrict__ count, int* __restrict__ row_start,
                             int* __restrict__ bsum) {
    const int r = blockIdx.x / NCHUNK;
    const int b = blockIdx.x % NCHUNK;
    const int tid = threadIdx.x;
    const int base = b * 1024 + tid * 4;
    int v[4];
#pragma unroll
    for (int i = 0; i < 4; ++i)
        v[i] = (base + i < N_NODES) ? count[r * N_NODES + base + i] : 0;
    const int tsum = v[0] + v[1] + v[2] + v[3];
    __shared__ int sd[256];
    sd[tid] = tsum;
    __syncthreads();
    for (int off = 1; off < 256; off <<= 1) {
        const int tv = (tid >= off) ? sd[tid - off] : 0;
        __syncthreads();
        sd[tid] += tv;
        __syncthreads();
    }
    int run = sd[tid] - tsum;
#pragma unroll
    for (int i = 0; i < 4; ++i) {
        if (base + i < N_NODES) row_start[r * N_NODES + base + i] = run;
        run += v[i];
    }
    if (tid == 255) bsum[blockIdx.x] = sd[255];
}

__global__ void scan2_kernel(int* __restrict__ bsum) {
    const int r = blockIdx.x;
    const int tid = threadIdx.x;
    const int v = (tid < NCHUNK) ? bsum[r * NCHUNK + tid] : 0;
    __shared__ int sd[256];
    sd[tid] = v;
    __syncthreads();
    for (int off = 1; off < 256; off <<= 1) {
        const int tv = (tid >= off) ? sd[tid - off] : 0;
        __syncthreads();
        sd[tid] += tv;
        __syncthreads();
    }
    if (tid < NCHUNK) bsum[r * NCHUNK + tid] = sd[tid] - v;
}

__global__ void scan3_kernel(int* __restrict__ row_start, const int* __restrict__ bsum) {
    const int r = blockIdx.x / NCHUNK;
    const int b = blockIdx.x % NCHUNK;
    const int add = bsum[blockIdx.x];
    const int base = b * 1024 + threadIdx.x * 4;
#pragma unroll
    for (int i = 0; i < 4; ++i)
        if (base + i < N_NODES) row_start[r * N_NODES + base + i] += add;
}

// fused score + CSR fill, atomic-free: pos = row_start[d] + rank[e].
__global__ void fill_kernel(const int* __restrict__ src, const int* __restrict__ dst,
                            const float* __restrict__ ps, const float* __restrict__ pd,
                            const float* __restrict__ att_b,
                            const int* __restrict__ row_start, const int* __restrict__ rank,
                            int2* __restrict__ edge_sorted, float* __restrict__ sums) {
    const int gid = blockIdx.x * 256 + threadIdx.x;
    const int r = blockIdx.x >> 10;
    const int s = src[gid];
    const int d = dst[gid];
    float sc = ps[r * N_NODES + s] + pd[r * N_NODES + d] + att_b[r];
    sc = sc > 0.f ? sc : SLOPE * sc;
    const float ev = __expf(sc);
    const int pos = row_start[r * N_NODES + d] + rank[gid];
    int2 pk;
    pk.x = s;
    pk.y = __float_as_int(ev);
    edge_sorted[(size_t)r * NEDGE + pos] = pk;
    float v = ev;
#pragma unroll
    for (int off = 32; off >= 1; off >>= 1) v += __shfl_xor(v, off);
    __shared__ float red[4];
    if ((threadIdx.x & 63) == 0) red[threadIdx.x >> 6] = v;
    __syncthreads();
    if (threadIdx.x == 0) {
        unsafeAtomicAdd(&sums[r], red[0] + red[1] + red[2] + red[3]);
    }
}

// twT[c][k] = bf16(tw[k][c] / sums[k/128]) ; tbs[k_rel] = tb / sums   (fold softmax denom)
__global__ void cast_kernel(const float* __restrict__ tw, const float* __restrict__ tb,
                            const float* __restrict__ sums,
                            unsigned short* __restrict__ twT, float* __restrict__ tbs) {
    const int c = blockIdx.x;      // 0..127
    const int kk = threadIdx.x;    // 0..383
    const float inv = 1.0f / sums[kk >> 7];
    twT[c * 384 + kk] = f2bf(tw[kk * 128 + c] * inv);
    if (c == 0) tbs[kk] = tb[kk] * inv;
}

// CSR gather of bf16 x: aggb[n][r*128+f] = bf16( sum_e ev_e * x_bf[src_e][f] );
// asum[r][n] = sum_e ev_e.
// One 16-LANE group per (r,n): ushort8 per lane; 4-deep edge batching for MLP;
// nontemporal aggb stores keep x_bf L2-resident.
__global__ void agg_kernel(const int* __restrict__ row_start,
                           const int2* __restrict__ edge_sorted,
                           const unsigned short* __restrict__ x_bf,
                           unsigned short* __restrict__ aggb, float* __restrict__ asum) {
    const int lane = threadIdx.x & 15;
    const int r = blockIdx.y;
    const int n = blockIdx.x * 16 + (threadIdx.x >> 4);
    const int beg = row_start[r * N_NODES + n];
    const int end = (n == N_NODES - 1) ? NEDGE : row_start[r * N_NODES + n + 1];
    const int2* es = edge_sorted + (size_t)r * NEDGE;

    float acc[8] = {0.f, 0.f, 0.f, 0.f, 0.f, 0.f, 0.f, 0.f};
    float asacc = 0.f;

    for (int i = beg; i < end; i += 4) {
        const int rem = end - i;
        int2 pk0, pk1, pk2, pk3;
        pk0 = es[i];
        if (rem > 1) pk1 = es[i + 1];
        if (rem > 2) pk2 = es[i + 2];
        if (rem > 3) pk3 = es[i + 3];
        u16x8 xv0, xv1, xv2, xv3;
        xv0 = *reinterpret_cast<const u16x8*>(x_bf + (size_t)pk0.x * FDIM + lane * 8);
        if (rem > 1) xv1 = *reinterpret_cast<const u16x8*>(x_bf + (size_t)pk1.x * FDIM + lane * 8);
        if (rem > 2) xv2 = *reinterpret_cast<const u16x8*>(x_bf + (size_t)pk2.x * FDIM + lane * 8);
        if (rem > 3) xv3 = *reinterpret_cast<const u16x8*>(x_bf + (size_t)pk3.x * FDIM + lane * 8);
        {
            const float a = __int_as_float(pk0.y);
            asacc += a;
#pragma unroll
            for (int d = 0; d < 8; ++d) acc[d] += a * bf2f(xv0[d]);
        }
        if (rem > 1) {
            const float a = __int_as_float(pk1.y);
            asacc += a;
#pragma unroll
            for (int d = 0; d < 8; ++d) acc[d] += a * bf2f(xv1[d]);
        }
        if (rem > 2) {
            const float a = __int_as_float(pk2.y);
            asacc += a;
#pragma unroll
            for (int d = 0; d < 8; ++d) acc[d] += a * bf2f(xv2[d]);
        }
        if (rem > 3) {
            const float a = __int_as_float(pk3.y);
            asacc += a;
#pragma unroll
            for (int d = 0; d < 8; ++d) acc[d] += a * bf2f(xv3[d]);
        }
    }

    u16x8 o;
#pragma unroll
    for (int d = 0; d < 8; ++d) o[d] = f2bf(acc[d]);
    i32x4* dst4 = reinterpret_cast<i32x4*>(aggb + (size_t)n * 384 + r * FDIM + lane * 8);
    __builtin_nontemporal_store(*reinterpret_cast<i32x4*>(&o), dst4);
    if (lane == 0) asum[r * N_NODES + n] = asacc;
}

// out[N][128] = relu( A[N][384](bf16) @ W + asum·tbs + h_bias ), MFMA 16x16x32 bf16
// BK=32, double-buffered sA+sB = 40 KB LDS -> 4 blocks/CU (16 waves/CU).
__global__ __launch_bounds__(256, 4)
void gemm_kernel(const unsigned short* __restrict__ A, const unsigned short* __restrict__ Bt,
                 const float* __restrict__ asum, const float* __restrict__ tbs,
                 const float* __restrict__ h_bias, float* __restrict__ out) {
    __shared__ unsigned short sA[2][128 * 40];  // 128 rows x (32 k + 8 pad)
    __shared__ unsigned short sB[2][128 * 40];  // 128 cols x (32 k + 8 pad)
    const int tid = threadIdx.x;
    const int row0 = blockIdx.x * 128;
    const int rs = tid >> 2;            // 0..63 (row/col group, +64 for i=1)
    const int koff = (tid & 3) * 8;     // 0,8,16,24 (element offset; 16 B chunk)

#pragma unroll
    for (int i = 0; i < 2; ++i) {
        const int rc = rs + i * 64;
        const int grow = row0 + rc;
        int4 va = {0, 0, 0, 0};
        if (grow < N_NODES)
            va = *reinterpret_cast<const int4*>(&A[(size_t)grow * 384 + koff]);
        *reinterpret_cast<int4*>(&sA[0][rc * 40 + koff]) = va;
        const int4 vb = *reinterpret_cast<const int4*>(&Bt[rc * 384 + koff]);
        *reinterpret_cast<int4*>(&sB[0][rc * 40 + koff]) = vb;
    }
    __syncthreads();

    const int w = tid >> 6, l = tid & 63;
    const int lr = l & 15, lk = l >> 4;
    f32x4 acc[2][8];
#pragma unroll
    for (int rt = 0; rt < 2; ++rt)
#pragma unroll
        for (int ct = 0; ct < 8; ++ct) acc[rt][ct] = (f32x4){0.f, 0.f, 0.f, 0.f};

    for (int ks = 0; ks < 12; ++ks) {
        const int buf = ks & 1;
        int4 ra[2], rb[2];
        if (ks < 11) {
            const int k0 = (ks + 1) * 32;
#pragma unroll
            for (int i = 0; i < 2; ++i) {
                const int rc = rs + i * 64;
                const int grow = row0 + rc;
                ra[i] = make_int4(0, 0, 0, 0);
                if (grow < N_NODES)
                    ra[i] = *reinterpret_cast<const int4*>(&A[(size_t)grow * 384 + k0 + koff]);
                rb[i] = *reinterpret_cast<const int4*>(&Bt[rc * 384 + k0 + koff]);
            }
        }
        bf16x8 afr[2];
#pragma unroll
        for (int rt = 0; rt < 2; ++rt)
            afr[rt] = *reinterpret_cast<const bf16x8*>(&sA[buf][(w * 32 + rt * 16 + lr) * 40 + lk * 8]);
#pragma unroll
        for (int ct = 0; ct < 8; ++ct) {
            const bf16x8 bfr = *reinterpret_cast<const bf16x8*>(&sB[buf][(ct * 16 + lr) * 40 + lk * 8]);
            acc[0][ct] = __builtin_amdgcn_mfma_f32_16x16x32_bf16(afr[0], bfr, acc[0][ct], 0, 0, 0);
            acc[1][ct] = __builtin_amdgcn_mfma_f32_16x16x32_bf16(afr[1], bfr, acc[1][ct], 0, 0, 0);
        }
        if (ks < 11) {
#pragma unroll
            for (int i = 0; i < 2; ++i) {
                const int rc = rs + i * 64;
                *reinterpret_cast<int4*>(&sA[buf ^ 1][rc * 40 + koff]) = ra[i];
                *reinterpret_cast<int4*>(&sB[buf ^ 1][rc * 40 + koff]) = rb[i];
            }
        }
        __syncthreads();
    }

    // epilogue: D row = (lane>>4)*4 + reg, col = lane&15  (m89-verified layout)
#pragma unroll
    for (int rt = 0; rt < 2; ++rt) {
        const int rowbase = row0 + w * 32 + rt * 16 + lk * 4;
        float as[RREL][4];
#pragma unroll
        for (int r = 0; r < RREL; ++r)
#pragma unroll
            for (int j = 0; j < 4; ++j)
                as[r][j] = (rowbase + j < N_NODES) ? asum[r * N_NODES + rowbase + j] : 0.f;
#pragma unroll
        for (int ct = 0; ct < 8; ++ct) {
            const int col = ct * 16 + lr;
            const float hb = h_bias[col];
            const float t0 = tbs[col], t1 = tbs[FDIM + col], t2 = tbs[2 * FDIM + col];
#pragma unroll
            for (int j = 0; j < 4; ++j) {
                const int row = rowbase + j;
                if (row < N_NODES) {
                    float v = acc[rt][ct][j] + as[0][j] * t0 + as[1][j] * t1 + as[2][j] * t2 + hb;
                    out[(size_t)row * FDIM + col] = fmaxf(v, 0.f);
                }
            }
        }
    }
}

extern "C" void kernel_launch(void* const* d_in, const int* in_sizes, int n_in,
                              void* d_out, int out_size, void* d_ws, size_t ws_size,
                              hipStream_t stream) {
    const float* x      = (const float*)d_in[0];
    const float* att_w  = (const float*)d_in[1];
    const float* att_b  = (const float*)d_in[2];
    const float* tw     = (const float*)d_in[3];
    const float* tb     = (const float*)d_in[4];
    const float* h_bias = (const float*)d_in[5];
    const int*   src    = (const int*)d_in[6];
    const int*   dst    = (const int*)d_in[7];
    float* out = (float*)d_out;

    float* wsf = (float*)d_ws;
    float* ps         = wsf + WS_PS;
    float* pd         = wsf + WS_PD;
    float* sums       = wsf + WS_SUMS;
    int*   count      = (int*)(wsf + WS_COUNT);
    int*   row_start  = (int*)(wsf + WS_ROWS);
    int*   bsum       = (int*)(wsf + WS_BSUM);
    int2*  edge_sorted= (int2*)(wsf + WS_ESORT);
    float* asum       = wsf + WS_ASUM;
    unsigned short* twT  = (unsigned short*)(wsf + WS_TWT);
    float* tbs        = wsf + WS_TBS;
    unsigned short* x_bf = (unsigned short*)(wsf + WS_XBF);
    unsigned short* aggb = (unsigned short*)(wsf + WS_AGGB);
    int*   rank       = (int*)(wsf + WS_RANK);

    hipMemsetAsync(sums, 0, 16 * sizeof(float), stream);
    hipMemsetAsync(count, 0, (size_t)RREL * N_NODES * sizeof(int), stream);

    proj_hist_kernel<<<PROJ_BLOCKS + HIST_BLOCKS, 256, 0, stream>>>(x, att_w, ps, pd, x_bf,
                                                                    dst, count, rank);

    scan1_kernel<<<RREL * NCHUNK, 256, 0, stream>>>(count, row_start, bsum);
    scan2_kernel<<<RREL, 256, 0, stream>>>(bsum);
    scan3_kernel<<<RREL * NCHUNK, 256, 0, stream>>>(row_start, bsum);

    fill_kernel<<<RREL * NEDGE / 256, 256, 0, stream>>>(src, dst, ps, pd, att_b,
                                                        row_start, rank, edge_sorted, sums);

    cast_kernel<<<FDIM, 384, 0, stream>>>(tw, tb, sums, twT, tbs);

    agg_kernel<<<dim3(N_NODES / 16, RREL), 256, 0, stream>>>(row_start, edge_sorted, x_bf,
                                                             aggb, asum);

    gemm_kernel<<<(N_NODES + 127) / 128, 256, 0, stream>>>(aggb, twT, asum, tbs, h_bias, out);
}

// Round 8
// 194.584 us; speedup vs baseline: 4.6568x; 1.0874x over previous
//
#include <hip/hip_runtime.h>
#include <hip/hip_bf16.h>

#define N_NODES 100000
#define FDIM 128
#define RREL 3
#define NEDGE 262144
#define SLOPE 0.2f
#define NCHUNK 98  // ceil(N_NODES/1024)
#define PROJ_BLOCKS 782                    // ceil(N_NODES/128)
#define HIST_BLOCKS (RREL * NEDGE / 256)   // 3072

typedef __attribute__((ext_vector_type(8))) short bf16x8;
typedef __attribute__((ext_vector_type(8))) unsigned short u16x8;
typedef __attribute__((ext_vector_type(4))) float f32x4;
typedef __attribute__((ext_vector_type(4))) int i32x4;

__device__ inline unsigned short f2bf(float f) {
    __hip_bfloat16 h = __float2bfloat16(f);
    return *reinterpret_cast<unsigned short*>(&h);
}
__device__ inline float bf2f(unsigned short u) {
    unsigned int b = ((unsigned int)u) << 16;
    return __int_as_float(b);
}

// -------- workspace layout (float units, 4 B each) --------
#define WS_PS    0          // R*N
#define WS_PD    300000     // R*N
#define WS_SUMS  600000     // 16
#define WS_COUNT 600016     // R*N  (histogram)
#define WS_ROWS  900016     // R*N  CSR row starts
#define WS_BSUM  1200016    // 512
#define WS_ESORT 1200528    // R*E int2 = 1572864 floats
#define WS_ASUM  2773392    // R*N
#define WS_TWT   3073392    // 49152 bf16 = 24576 floats (inv-scaled, transposed tw)
#define WS_TBS   3097968    // 384 (inv-scaled tb)
#define WS_XBF   3098352    // N*128 bf16 = 6.4M floats
#define WS_AGGB  9498352    // N*384 bf16 = 19.2M floats
#define WS_RANK  28698352   // R*E ints

// fused kernel:
//  blocks [0, PROJ_BLOCKS): MFMA-based projections P = x @ [w_s|w_d] (6 cols)
//    + bf16 cast of x to x_bf.  No cross-lane shuffles.
//  blocks [PROJ_BLOCKS, +HIST_BLOCKS): dst histogram per relation, capturing
//    each edge's bucket rank from the atomic return.
__global__ __launch_bounds__(256, 4)
void proj_hist_kernel(const float* __restrict__ x,
                      const float* __restrict__ att_w,
                      float* __restrict__ ps, float* __restrict__ pd,
                      unsigned short* __restrict__ x_bf,
                      const int* __restrict__ dst, int* __restrict__ count,
                      int* __restrict__ rank) {
    if (blockIdx.x >= PROJ_BLOCKS) {
        const int b = blockIdx.x - PROJ_BLOCKS;
        const int gid = b * 256 + threadIdx.x;
        const int r = b >> 10;
        rank[gid] = atomicAdd(&count[r * N_NODES + dst[gid]], 1);
        return;
    }
    __shared__ unsigned short sX[128 * 136];  // 128 rows x (128 k + 8 pad)
    __shared__ unsigned short sW[16 * 136];   // 16 cols (6 valid) x 128 k
    const int tid = threadIdx.x;
    const int row0 = blockIdx.x * 128;

    // stage W: col c<3 -> w_s[c][k] = att_w[c*256+k]; c in 3..5 -> w_d[c-3][k]
#pragma unroll
    for (int i = 0; i < 8; ++i) {
        const int idx = tid + i * 256;
        const int c = idx >> 7, k = idx & 127;
        float v = 0.f;
        if (c < 3) v = att_w[c * 256 + k];
        else if (c < 6) v = att_w[(c - 3) * 256 + 128 + k];
        sW[c * 136 + k] = f2bf(v);
    }
    // stage X tile (bf16) + emit global x_bf
    const int g = tid >> 5, lane = tid & 31;
#pragma unroll
    for (int it = 0; it < 16; ++it) {
        const int rrow = it * 8 + g;
        const int row = row0 + rrow;
        float4 xv = make_float4(0.f, 0.f, 0.f, 0.f);
        if (row < N_NODES) xv = *reinterpret_cast<const float4*>(x + (size_t)row * FDIM + lane * 4);
        ushort4 u;
        u.x = f2bf(xv.x); u.y = f2bf(xv.y); u.z = f2bf(xv.z); u.w = f2bf(xv.w);
        if (row < N_NODES)
            *reinterpret_cast<ushort4*>(x_bf + (size_t)row * FDIM + lane * 4) = u;
        *reinterpret_cast<ushort4*>(&sX[rrow * 136 + lane * 4]) = u;
    }
    __syncthreads();

    const int w = tid >> 6, l = tid & 63;
    const int lr = l & 15, lk = l >> 4;
    f32x4 acc[2];
    acc[0] = (f32x4){0.f, 0.f, 0.f, 0.f};
    acc[1] = (f32x4){0.f, 0.f, 0.f, 0.f};
#pragma unroll
    for (int ks = 0; ks < 4; ++ks) {
        const bf16x8 bfr = *reinterpret_cast<const bf16x8*>(&sW[lr * 136 + ks * 32 + lk * 8]);
#pragma unroll
        for (int rt = 0; rt < 2; ++rt) {
            const bf16x8 afr =
                *reinterpret_cast<const bf16x8*>(&sX[(w * 32 + rt * 16 + lr) * 136 + ks * 32 + lk * 8]);
            acc[rt] = __builtin_amdgcn_mfma_f32_16x16x32_bf16(afr, bfr, acc[rt], 0, 0, 0);
        }
    }
    // epilogue: D row = (lane>>4)*4 + reg, col = lane&15; cols 0..2 -> ps, 3..5 -> pd
    if (lr < 6) {
        float* base = (lr < 3) ? (ps + lr * N_NODES) : (pd + (lr - 3) * N_NODES);
#pragma unroll
        for (int rt = 0; rt < 2; ++rt) {
            const int rowbase = row0 + w * 32 + rt * 16 + lk * 4;
#pragma unroll
            for (int j = 0; j < 4; ++j) {
                const int row = rowbase + j;
                if (row < N_NODES) base[row] = acc[rt][j];
            }
        }
    }
}

// ---- exclusive prefix scan of count -> row_start ----
__global__ void scan1_kernel(const int* __restrict__ count, int* __restrict__ row_start,
                             int* __restrict__ bsum) {
    const int r = blockIdx.x / NCHUNK;
    const int b = blockIdx.x % NCHUNK;
    const int tid = threadIdx.x;
    const int base = b * 1024 + tid * 4;
    int v[4];
#pragma unroll
    for (int i = 0; i < 4; ++i)
        v[i] = (base + i < N_NODES) ? count[r * N_NODES + base + i] : 0;
    const int tsum = v[0] + v[1] + v[2] + v[3];
    __shared__ int sd[256];
    sd[tid] = tsum;
    __syncthreads();
    for (int off = 1; off < 256; off <<= 1) {
        const int tv = (tid >= off) ? sd[tid - off] : 0;
        __syncthreads();
        sd[tid] += tv;
        __syncthreads();
    }
    int run = sd[tid] - tsum;
#pragma unroll
    for (int i = 0; i < 4; ++i) {
        if (base + i < N_NODES) row_start[r * N_NODES + base + i] = run;
        run += v[i];
    }
    if (tid == 255) bsum[blockIdx.x] = sd[255];
}

__global__ void scan2_kernel(int* __restrict__ bsum) {
    const int r = blockIdx.x;
    const int tid = threadIdx.x;
    const int v = (tid < NCHUNK) ? bsum[r * NCHUNK + tid] : 0;
    __shared__ int sd[256];
    sd[tid] = v;
    __syncthreads();
    for (int off = 1; off < 256; off <<= 1) {
        const int tv = (tid >= off) ? sd[tid - off] : 0;
        __syncthreads();
        sd[tid] += tv;
        __syncthreads();
    }
    if (tid < NCHUNK) bsum[r * NCHUNK + tid] = sd[tid] - v;
}

__global__ void scan3_kernel(int* __restrict__ row_start, const int* __restrict__ bsum) {
    const int r = blockIdx.x / NCHUNK;
    const int b = blockIdx.x % NCHUNK;
    const int add = bsum[blockIdx.x];
    const int base = b * 1024 + threadIdx.x * 4;
#pragma unroll
    for (int i = 0; i < 4; ++i)
        if (base + i < N_NODES) row_start[r * N_NODES + base + i] += add;
}

// fused score + CSR fill, atomic-free: pos = row_start[d] + rank[e].
__global__ void fill_kernel(const int* __restrict__ src, const int* __restrict__ dst,
                            const float* __restrict__ ps, const float* __restrict__ pd,
                            const float* __restrict__ att_b,
                            const int* __restrict__ row_start, const int* __restrict__ rank,
                            int2* __restrict__ edge_sorted, float* __restrict__ sums) {
    const int gid = blockIdx.x * 256 + threadIdx.x;
    const int r = blockIdx.x >> 10;
    const int s = src[gid];
    const int d = dst[gid];
    float sc = ps[r * N_NODES + s] + pd[r * N_NODES + d] + att_b[r];
    sc = sc > 0.f ? sc : SLOPE * sc;
    const float ev = __expf(sc);
    const int pos = row_start[r * N_NODES + d] + rank[gid];
    int2 pk;
    pk.x = s;
    pk.y = __float_as_int(ev);
    edge_sorted[(size_t)r * NEDGE + pos] = pk;
    float v = ev;
#pragma unroll
    for (int off = 32; off >= 1; off >>= 1) v += __shfl_xor(v, off);
    __shared__ float red[4];
    if ((threadIdx.x & 63) == 0) red[threadIdx.x >> 6] = v;
    __syncthreads();
    if (threadIdx.x == 0) {
        unsafeAtomicAdd(&sums[r], red[0] + red[1] + red[2] + red[3]);
    }
}

// twT[c][k] = bf16(tw[k][c] / sums[k/128]) ; tbs[k_rel] = tb / sums   (fold softmax denom)
__global__ void cast_kernel(const float* __restrict__ tw, const float* __restrict__ tb,
                            const float* __restrict__ sums,
                            unsigned short* __restrict__ twT, float* __restrict__ tbs) {
    const int c = blockIdx.x;      // 0..127
    const int kk = threadIdx.x;    // 0..383
    const float inv = 1.0f / sums[kk >> 7];
    twT[c * 384 + kk] = f2bf(tw[kk * 128 + c] * inv);
    if (c == 0) tbs[kk] = tb[kk] * inv;
}

// CSR gather of bf16 x: aggb[n][r*128+f] = bf16( sum_e ev_e * x_bf[src_e][f] );
// asum[r][n] = sum_e ev_e.
// One 16-LANE group per (r,n): ushort8 per lane; 4-deep edge batching for MLP;
// nontemporal aggb stores keep x_bf L2-resident.
__global__ void agg_kernel(const int* __restrict__ row_start,
                           const int2* __restrict__ edge_sorted,
                           const unsigned short* __restrict__ x_bf,
                           unsigned short* __restrict__ aggb, float* __restrict__ asum) {
    const int lane = threadIdx.x & 15;
    const int r = blockIdx.y;
    const int n = blockIdx.x * 16 + (threadIdx.x >> 4);
    const int beg = row_start[r * N_NODES + n];
    const int end = (n == N_NODES - 1) ? NEDGE : row_start[r * N_NODES + n + 1];
    const int2* es = edge_sorted + (size_t)r * NEDGE;

    float acc[8] = {0.f, 0.f, 0.f, 0.f, 0.f, 0.f, 0.f, 0.f};
    float asacc = 0.f;

    for (int i = beg; i < end; i += 4) {
        const int rem = end - i;
        int2 pk0, pk1, pk2, pk3;
        pk0 = es[i];
        if (rem > 1) pk1 = es[i + 1];
        if (rem > 2) pk2 = es[i + 2];
        if (rem > 3) pk3 = es[i + 3];
        u16x8 xv0, xv1, xv2, xv3;
        xv0 = *reinterpret_cast<const u16x8*>(x_bf + (size_t)pk0.x * FDIM + lane * 8);
        if (rem > 1) xv1 = *reinterpret_cast<const u16x8*>(x_bf + (size_t)pk1.x * FDIM + lane * 8);
        if (rem > 2) xv2 = *reinterpret_cast<const u16x8*>(x_bf + (size_t)pk2.x * FDIM + lane * 8);
        if (rem > 3) xv3 = *reinterpret_cast<const u16x8*>(x_bf + (size_t)pk3.x * FDIM + lane * 8);
        {
            const float a = __int_as_float(pk0.y);
            asacc += a;
#pragma unroll
            for (int d = 0; d < 8; ++d) acc[d] += a * bf2f(xv0[d]);
        }
        if (rem > 1) {
            const float a = __int_as_float(pk1.y);
            asacc += a;
#pragma unroll
            for (int d = 0; d < 8; ++d) acc[d] += a * bf2f(xv1[d]);
        }
        if (rem > 2) {
            const float a = __int_as_float(pk2.y);
            asacc += a;
#pragma unroll
            for (int d = 0; d < 8; ++d) acc[d] += a * bf2f(xv2[d]);
        }
        if (rem > 3) {
            const float a = __int_as_float(pk3.y);
            asacc += a;
#pragma unroll
            for (int d = 0; d < 8; ++d) acc[d] += a * bf2f(xv3[d]);
        }
    }

    u16x8 o;
#pragma unroll
    for (int d = 0; d < 8; ++d) o[d] = f2bf(acc[d]);
    i32x4* dst4 = reinterpret_cast<i32x4*>(aggb + (size_t)n * 384 + r * FDIM + lane * 8);
    __builtin_nontemporal_store(*reinterpret_cast<i32x4*>(&o), dst4);
    if (lane == 0) asum[r * N_NODES + n] = asacc;
}

// out[N][128] = relu( A[N][384](bf16) @ W + asum·tbs + h_bias ), MFMA 16x16x32 bf16
// BK=32, double-buffered sA+sB = 40 KB LDS -> 4 blocks/CU (16 waves/CU).
__global__ __launch_bounds__(256, 4)
void gemm_kernel(const unsigned short* __restrict__ A, const unsigned short* __restrict__ Bt,
                 const float* __restrict__ asum, const float* __restrict__ tbs,
                 const float* __restrict__ h_bias, float* __restrict__ out) {
    __shared__ unsigned short sA[2][128 * 40];  // 128 rows x (32 k + 8 pad)
    __shared__ unsigned short sB[2][128 * 40];  // 128 cols x (32 k + 8 pad)
    const int tid = threadIdx.x;
    const int row0 = blockIdx.x * 128;
    const int rs = tid >> 2;            // 0..63 (row/col group, +64 for i=1)
    const int koff = (tid & 3) * 8;     // 0,8,16,24 (element offset; 16 B chunk)

#pragma unroll
    for (int i = 0; i < 2; ++i) {
        const int rc = rs + i * 64;
        const int grow = row0 + rc;
        int4 va = {0, 0, 0, 0};
        if (grow < N_NODES)
            va = *reinterpret_cast<const int4*>(&A[(size_t)grow * 384 + koff]);
        *reinterpret_cast<int4*>(&sA[0][rc * 40 + koff]) = va;
        const int4 vb = *reinterpret_cast<const int4*>(&Bt[rc * 384 + koff]);
        *reinterpret_cast<int4*>(&sB[0][rc * 40 + koff]) = vb;
    }
    __syncthreads();

    const int w = tid >> 6, l = tid & 63;
    const int lr = l & 15, lk = l >> 4;
    f32x4 acc[2][8];
#pragma unroll
    for (int rt = 0; rt < 2; ++rt)
#pragma unroll
        for (int ct = 0; ct < 8; ++ct) acc[rt][ct] = (f32x4){0.f, 0.f, 0.f, 0.f};

    for (int ks = 0; ks < 12; ++ks) {
        const int buf = ks & 1;
        int4 ra[2], rb[2];
        if (ks < 11) {
            const int k0 = (ks + 1) * 32;
#pragma unroll
            for (int i = 0; i < 2; ++i) {
                const int rc = rs + i * 64;
                const int grow = row0 + rc;
                ra[i] = make_int4(0, 0, 0, 0);
                if (grow < N_NODES)
                    ra[i] = *reinterpret_cast<const int4*>(&A[(size_t)grow * 384 + k0 + koff]);
                rb[i] = *reinterpret_cast<const int4*>(&Bt[rc * 384 + k0 + koff]);
            }
        }
        bf16x8 afr[2];
#pragma unroll
        for (int rt = 0; rt < 2; ++rt)
            afr[rt] = *reinterpret_cast<const bf16x8*>(&sA[buf][(w * 32 + rt * 16 + lr) * 40 + lk * 8]);
#pragma unroll
        for (int ct = 0; ct < 8; ++ct) {
            const bf16x8 bfr = *reinterpret_cast<const bf16x8*>(&sB[buf][(ct * 16 + lr) * 40 + lk * 8]);
            acc[0][ct] = __builtin_amdgcn_mfma_f32_16x16x32_bf16(afr[0], bfr, acc[0][ct], 0, 0, 0);
            acc[1][ct] = __builtin_amdgcn_mfma_f32_16x16x32_bf16(afr[1], bfr, acc[1][ct], 0, 0, 0);
        }
        if (ks < 11) {
#pragma unroll
            for (int i = 0; i < 2; ++i) {
                const int rc = rs + i * 64;
                *reinterpret_cast<int4*>(&sA[buf ^ 1][rc * 40 + koff]) = ra[i];
                *reinterpret_cast<int4*>(&sB[buf ^ 1][rc * 40 + koff]) = rb[i];
            }
        }
        __syncthreads();
    }

    // epilogue: D row = (lane>>4)*4 + reg, col = lane&15  (m89-verified layout)
#pragma unroll
    for (int rt = 0; rt < 2; ++rt) {
        const int rowbase = row0 + w * 32 + rt * 16 + lk * 4;
        float as[RREL][4];
#pragma unroll
        for (int r = 0; r < RREL; ++r)
#pragma unroll
            for (int j = 0; j < 4; ++j)
                as[r][j] = (rowbase + j < N_NODES) ? asum[r * N_NODES + rowbase + j] : 0.f;
#pragma unroll
        for (int ct = 0; ct < 8; ++ct) {
            const int col = ct * 16 + lr;
            const float hb = h_bias[col];
            const float t0 = tbs[col], t1 = tbs[FDIM + col], t2 = tbs[2 * FDIM + col];
#pragma unroll
            for (int j = 0; j < 4; ++j) {
                const int row = rowbase + j;
                if (row < N_NODES) {
                    float v = acc[rt][ct][j] + as[0][j] * t0 + as[1][j] * t1 + as[2][j] * t2 + hb;
                    out[(size_t)row * FDIM + col] = fmaxf(v, 0.f);
                }
            }
        }
    }
}

extern "C" void kernel_launch(void* const* d_in, const int* in_sizes, int n_in,
                              void* d_out, int out_size, void* d_ws, size_t ws_size,
                              hipStream_t stream) {
    const float* x      = (const float*)d_in[0];
    const float* att_w  = (const float*)d_in[1];
    const float* att_b  = (const float*)d_in[2];
    const float* tw     = (const float*)d_in[3];
    const float* tb     = (const float*)d_in[4];
    const float* h_bias = (const float*)d_in[5];
    const int*   src    = (const int*)d_in[6];
    const int*   dst    = (const int*)d_in[7];
    float* out = (float*)d_out;

    float* wsf = (float*)d_ws;
    float* ps         = wsf + WS_PS;
    float* pd         = wsf + WS_PD;
    float* sums       = wsf + WS_SUMS;
    int*   count      = (int*)(wsf + WS_COUNT);
    int*   row_start  = (int*)(wsf + WS_ROWS);
    int*   bsum       = (int*)(wsf + WS_BSUM);
    int2*  edge_sorted= (int2*)(wsf + WS_ESORT);
    float* asum       = wsf + WS_ASUM;
    unsigned short* twT  = (unsigned short*)(wsf + WS_TWT);
    float* tbs        = wsf + WS_TBS;
    unsigned short* x_bf = (unsigned short*)(wsf + WS_XBF);
    unsigned short* aggb = (unsigned short*)(wsf + WS_AGGB);
    int*   rank       = (int*)(wsf + WS_RANK);

    hipMemsetAsync(sums, 0, 16 * sizeof(float), stream);
    hipMemsetAsync(count, 0, (size_t)RREL * N_NODES * sizeof(int), stream);

    proj_hist_kernel<<<PROJ_BLOCKS + HIST_BLOCKS, 256, 0, stream>>>(x, att_w, ps, pd, x_bf,
                                                                    dst, count, rank);

    scan1_kernel<<<RREL * NCHUNK, 256, 0, stream>>>(count, row_start, bsum);
    scan2_kernel<<<RREL, 256, 0, stream>>>(bsum);
    scan3_kernel<<<RREL * NCHUNK, 256, 0, stream>>>(row_start, bsum);

    fill_kernel<<<RREL * NEDGE / 256, 256, 0, stream>>>(src, dst, ps, pd, att_b,
                                                        row_start, rank, edge_sorted, sums);

    cast_kernel<<<FDIM, 384, 0, stream>>>(tw, tb, sums, twT, tbs);

    agg_kernel<<<dim3(N_NODES / 16, RREL), 256, 0, stream>>>(row_start, edge_sorted, x_bf,
                                                             aggb, asum);

    gemm_kernel<<<(N_NODES + 127) / 128, 256, 0, stream>>>(aggb, twT, asum, tbs, h_bias, out);
}